// Round 2
// baseline (411.958 us; speedup 1.0000x reference)
//
#include <hip/hip_runtime.h>
#include <hip/hip_bf16.h>
#include <stdint.h>

// Problem constants
#define NB 8
#define NN 1024
#define ND 128
// Bmat layout: [B][N][6][128] bf16 (uint16_t); row stride per (b,i) = 768 elems = 1536 BYTES.

__device__ __forceinline__ uint16_t f2bf(float f) {
    union { float f; uint32_t u; } v; v.f = f;
    uint32_t u = v.u;
    // round-to-nearest-even to bf16 (inputs are finite/sane here)
    uint32_t r = (u + 0x7FFFu + ((u >> 16) & 1u)) >> 16;
    return (uint16_t)r;
}

// ---------------------------------------------------------------------------
// Kernel 1: Bmat[b,i,r,e] = sum_d X[b,i,d] * W[r,e,d] + bias[r,e]   (bf16 out)
// Viewed as GEMM: C[8192 x 768] = X[8192 x 128] @ W^T, W row-major [768 x 128].
// Tile: 128(m) x 128(n), Kc=64 (2 chunks), 256 threads, 8x8 micro-tile.
// ---------------------------------------------------------------------------
__global__ __launch_bounds__(256, 2)
void bmat_gemm(const float* __restrict__ X, const float* __restrict__ W,
               const float* __restrict__ bias, uint16_t* __restrict__ Bmat) {
    const int bm  = blockIdx.x;        // 0..63  -> m0 = bm*128
    const int nt  = blockIdx.y;        // 0..5   -> n0 = nt*128  (768 cols total)
    const int tid = threadIdx.x;
    const int tx  = tid & 15;          // n-dir
    const int ty  = tid >> 4;          // m-dir
    const int m0  = bm * 128;

    __shared__ float As[64][132];      // As[d][m]
    __shared__ float Bs[64][132];      // Bs[d][n]

    float acc[8][8];
#pragma unroll
    for (int i = 0; i < 8; ++i)
#pragma unroll
        for (int j = 0; j < 8; ++j) acc[i][j] = 0.f;

    for (int kc = 0; kc < 2; ++kc) {
        // stage A: X rows m0..m0+127, cols kc*64..+63 -> transposed into As
#pragma unroll
        for (int s = 0; s < 8; ++s) {
            int f   = tid + s * 256;   // 0..2047
            int row = f >> 4;          // 0..127 (m-local)
            int c4  = f & 15;          // 0..15  (d-group)
            float4 v = *(const float4*)&X[(size_t)(m0 + row) * 128 + kc * 64 + c4 * 4];
            As[c4 * 4 + 0][row] = v.x;
            As[c4 * 4 + 1][row] = v.y;
            As[c4 * 4 + 2][row] = v.z;
            As[c4 * 4 + 3][row] = v.w;
        }
        // stage B: W rows nt*128..+127 (re), cols kc*64..+63 (d) -> Bs[d][n]
#pragma unroll
        for (int s = 0; s < 8; ++s) {
            int f   = tid + s * 256;
            int row = f >> 4;          // n-local 0..127
            int c4  = f & 15;
            float4 v = *(const float4*)&W[(size_t)(nt * 128 + row) * 128 + kc * 64 + c4 * 4];
            Bs[c4 * 4 + 0][row] = v.x;
            Bs[c4 * 4 + 1][row] = v.y;
            Bs[c4 * 4 + 2][row] = v.z;
            Bs[c4 * 4 + 3][row] = v.w;
        }
        __syncthreads();

#pragma unroll 4
        for (int d = 0; d < 64; ++d) {
            float4 a0 = *(const float4*)&As[d][ty * 8];
            float4 a1 = *(const float4*)&As[d][ty * 8 + 4];
            float4 b0 = *(const float4*)&Bs[d][tx * 8];
            float4 b1 = *(const float4*)&Bs[d][tx * 8 + 4];
            float am[8] = {a0.x, a0.y, a0.z, a0.w, a1.x, a1.y, a1.z, a1.w};
            float bn[8] = {b0.x, b0.y, b0.z, b0.w, b1.x, b1.y, b1.z, b1.w};
#pragma unroll
            for (int mi = 0; mi < 8; ++mi)
#pragma unroll
                for (int ni = 0; ni < 8; ++ni)
                    acc[mi][ni] += am[mi] * bn[ni];
        }
        __syncthreads();
    }

    // epilogue: add bias, convert to bf16, store 8 contiguous per row
    const int col0 = nt * 128 + tx * 8;
    float bs[8];
#pragma unroll
    for (int ni = 0; ni < 8; ++ni) bs[ni] = bias[col0 + ni];

#pragma unroll
    for (int mi = 0; mi < 8; ++mi) {
        int m = m0 + ty * 8 + mi;
        uint16_t t[8];
#pragma unroll
        for (int ni = 0; ni < 8; ++ni) t[ni] = f2bf(acc[mi][ni] + bs[ni]);
        uint4 pk;
        pk.x = (uint32_t)t[0] | ((uint32_t)t[1] << 16);
        pk.y = (uint32_t)t[2] | ((uint32_t)t[3] << 16);
        pk.z = (uint32_t)t[4] | ((uint32_t)t[5] << 16);
        pk.w = (uint32_t)t[6] | ((uint32_t)t[7] << 16);
        *(uint4*)&Bmat[(size_t)m * 768 + col0] = pk;
    }
}

// ---------------------------------------------------------------------------
// Kernel 2: out[b,j,:] = symbols[b,j,:] + sum_{i != j} Bmat[b,i,rel(b,i,j),:]
// Block = 256 threads = 4 waves; each wave owns 2 j's (half-wave each).
// Phase 1: classify rel(i,j) for the block's 8 j's into LDS (sentinel 6 at i==j).
// Phase 2: each half-wave (32 lanes) gathers bf16 rows; lane covers 4 e's.
// ---------------------------------------------------------------------------
__global__ __launch_bounds__(256, 8)
void gather_kernel(const float* __restrict__ sym, const float* __restrict__ pos,
                   const uint16_t* __restrict__ Bmat, float* __restrict__ out) {
    const int blk  = blockIdx.x;          // 0..1023
    const int b    = blk >> 7;            // 0..7
    const int j0   = (blk & 127) * 8;     // 8 j's per block
    const int tid  = threadIdx.x;
    const int w    = tid >> 6;            // wave 0..3
    const int lane = tid & 63;

    __shared__ uint32_t relu[8][256];     // [j-slot][i/4] packed relation bytes

    const float2* pos2 = (const float2*)pos;

    // ---- phase 1: classification ----
#pragma unroll
    for (int jj = 0; jj < 2; ++jj) {
        const int jslot = 2 * w + jj;
        const int j = j0 + jslot;
        const float2 pj = pos2[(b << 10) + j];
        for (int it = 0; it < 4; ++it) {
            int ib = it * 256 + lane * 4;
            uint32_t pack = 0;
#pragma unroll
            for (int q = 0; q < 4; ++q) {
                int i = ib + q;
                float2 pi = pos2[(b << 10) + i];
                float dx = pj.x - pi.x;
                float dy = pj.y - pi.y;
                // faithful priority chain of _get_relation_type
                int r = (dy > 0.5f) ? 0
                      : (dy < -0.5f) ? 1
                      : (dx < -0.5f) ? 2
                      : (dx > 0.5f)  ? 3
                      : (fabsf(dx) < 0.3f && fabsf(dy) < 0.3f) ? 4
                      : 5;
                if (i == j) r = 6;  // diagonal: excluded
                pack |= ((uint32_t)r) << (8 * q);
            }
            relu[jslot][ib >> 2] = pack;
        }
    }
    __syncthreads();

    // ---- phase 2: gather-accumulate ----
    const int jl    = lane >> 5;          // which j of this wave's pair
    const int jslot = 2 * w + jl;
    const int j     = j0 + jslot;
    const int sub   = lane & 31;          // e-group: e = sub*4 .. sub*4+3

    // byte base: Bmat + b*N*6*128*2 bytes + sub*8 bytes
    const char* bbase = (const char*)Bmat + ((size_t)b * (1024u * 1536u)) + sub * 8;

    float a0 = 0.f, a1 = 0.f, a2 = 0.f, a3 = 0.f;
    for (int i4 = 0; i4 < 256; ++i4) {
        uint32_t ru = relu[jslot][i4];
        size_t rowb = (size_t)i4 * 6144;   // 4 i-rows per i4, 1536 BYTES per i-row
#pragma unroll
        for (int q = 0; q < 4; ++q) {
            uint32_t r = (ru >> (8 * q)) & 255u;
            if (r < 6u) {  // r==6 only at i==j: half-wave-uniform, almost never taken
                const uint2* p = (const uint2*)(bbase + rowb + (size_t)q * 1536 + (r << 8));
                uint2 v = *p;
                a0 += __uint_as_float(v.x << 16);
                a1 += __uint_as_float(v.x & 0xFFFF0000u);
                a2 += __uint_as_float(v.y << 16);
                a3 += __uint_as_float(v.y & 0xFFFF0000u);
            }
        }
    }

    // ---- epilogue ----
    size_t o = ((size_t)((b << 10) + j) << 7) + (size_t)sub * 4;
    float4 s = *(const float4*)&sym[o];
    float4 res;
    res.x = s.x + a0;
    res.y = s.y + a1;
    res.z = s.z + a2;
    res.w = s.w + a3;
    *(float4*)&out[o] = res;
}

extern "C" void kernel_launch(void* const* d_in, const int* in_sizes, int n_in,
                              void* d_out, int out_size, void* d_ws, size_t ws_size,
                              hipStream_t stream) {
    const float* symbols   = (const float*)d_in[0];  // [8,1024,128]
    const float* positions = (const float*)d_in[1];  // [8,1024,2]
    const float* W         = (const float*)d_in[2];  // [6,128,128]
    const float* bias      = (const float*)d_in[3];  // [6,128]
    float* out             = (float*)d_out;          // [8,1024,128]
    uint16_t* Bmat         = (uint16_t*)d_ws;        // [8,1024,6,128] bf16 = 12.6 MB

    bmat_gemm<<<dim3(64, 6), dim3(256), 0, stream>>>(symbols, W, bias, Bmat);
    gather_kernel<<<dim3(1024), dim3(256), 0, stream>>>(symbols, positions, Bmat, out);
}

// Round 3
// 184.290 us; speedup vs baseline: 2.2354x; 2.2354x over previous
//
#include <hip/hip_runtime.h>
#include <stdint.h>

// Problem: out[b,j,:] = sym[b,j,:] + sum_{i!=j} (sym[b,i,:] @ W[rel(i,j)].T + bias[rel(i,j)])
// B=8, N=1024, D=128, 6 relations.
//
// Pipeline:
//  1. split_kernel: X(fp32)->Xh,Xl(bf16), W->Wh,Wl  (split-bf16 for ~fp32-accurate MFMA)
//  2. bmat_mfma:   BmatT[b][r*128+e][i] = sum_d W[r,e,d]*X[b,i,d] + bias[r,e]  (bf16, i-contiguous)
//  3. agg_mfma:    6 masked GEMMs agg[j,e] += M_r[j,i] * BmatT[b][r][e][i], mask synthesized
//                  in registers from an LDS relation-code table; M entries are exact 0/1.

typedef __attribute__((ext_vector_type(8))) short bf16x8;
typedef __attribute__((ext_vector_type(4))) float f32x4;

union U4B { uint4 u; bf16x8 b; };

__device__ __forceinline__ uint16_t f2bf(float f) {
    union { float f; uint32_t u; } v; v.f = f;
    uint32_t u = v.u;
    uint32_t r = (u + 0x7FFFu + ((u >> 16) & 1u)) >> 16;  // RNE
    return (uint16_t)r;
}
__device__ __forceinline__ float bf2f(uint16_t h) {
    union { uint32_t u; float f; } v; v.u = ((uint32_t)h) << 16; return v.f;
}

// ---------------------------------------------------------------------------
// Kernel 1: split fp32 -> (hi, lo) bf16 pairs.  X: 8*1024*128 = 1,048,576 floats
// (262144 float4), W: 768*128 = 98,304 floats (24576 float4). Grid 1120*256.
// ---------------------------------------------------------------------------
__global__ __launch_bounds__(256)
void split_kernel(const float* __restrict__ X, const float* __restrict__ W,
                  uint16_t* __restrict__ Xh, uint16_t* __restrict__ Xl,
                  uint16_t* __restrict__ Wh, uint16_t* __restrict__ Wl) {
    int idx = blockIdx.x * 256 + threadIdx.x;
    const float* src; uint16_t* dh; uint16_t* dl; int base;
    if (idx < 262144) { src = X; dh = Xh; dl = Xl; base = idx; }
    else {
        base = idx - 262144;
        if (base >= 24576) return;
        src = W; dh = Wh; dl = Wl;
    }
    float4 v = ((const float4*)src)[base];
    uint16_t h0 = f2bf(v.x), h1 = f2bf(v.y), h2 = f2bf(v.z), h3 = f2bf(v.w);
    uint16_t l0 = f2bf(v.x - bf2f(h0)), l1 = f2bf(v.y - bf2f(h1));
    uint16_t l2 = f2bf(v.z - bf2f(h2)), l3 = f2bf(v.w - bf2f(h3));
    uint2 ph = { (uint32_t)h0 | ((uint32_t)h1 << 16), (uint32_t)h2 | ((uint32_t)h3 << 16) };
    uint2 pl = { (uint32_t)l0 | ((uint32_t)l1 << 16), (uint32_t)l2 | ((uint32_t)l3 << 16) };
    *(uint2*)&dh[(size_t)base * 4] = ph;
    *(uint2*)&dl[(size_t)base * 4] = pl;
}

// ---------------------------------------------------------------------------
// Kernel 2: BmatT[(b*768 + re)*1024 + i] = bf16( sum_d W[re,d]*X[b,i,d] + bias[re] )
// Split-GEMM: WhXh + WhXl + WlXh (K=3x128). Pure-register MFMA, direct global frags.
// Wave tile 32m(re) x 64n(i); block 256 thr = 4 waves (n-split). Grid 768.
// ---------------------------------------------------------------------------
__global__ __launch_bounds__(256)
void bmat_mfma(const uint16_t* __restrict__ Wh, const uint16_t* __restrict__ Wl,
               const uint16_t* __restrict__ Xh, const uint16_t* __restrict__ Xl,
               const float* __restrict__ bias, uint16_t* __restrict__ BmatT) {
    const int x = blockIdx.x;
    const int b = x & 7;               // XCD-locality: same b -> same XCD
    const int rest = x >> 3;           // 0..95
    const int mt = rest % 24;          // m0 = mt*32  (re-dim, 768)
    const int nt = rest / 24;          // 0..3
    const int tid = threadIdx.x, w = tid >> 6, lane = tid & 63;
    const int m = lane & 15, q = lane >> 4;
    const int m0 = mt * 32;
    const int n0 = nt * 256 + w * 64;  // i-dim

    const uint16_t* Xb_h = Xh + (size_t)b * 131072;  // 1024*128
    const uint16_t* Xb_l = Xl + (size_t)b * 131072;

    f32x4 acc[2][4];
#pragma unroll
    for (int a = 0; a < 2; ++a)
#pragma unroll
        for (int n = 0; n < 4; ++n) acc[a][n] = (f32x4){0.f, 0.f, 0.f, 0.f};

#pragma unroll
    for (int c = 0; c < 3; ++c) {
        const uint16_t* Ap = (c < 2) ? Wh : Wl;
        const uint16_t* Bp = (c == 1) ? Xb_l : Xb_h;
#pragma unroll
        for (int d0 = 0; d0 < 128; d0 += 32) {
            U4B a0, a1, bb[4];
            a0.u = *(const uint4*)&Ap[(size_t)(m0 + m) * 128 + d0 + q * 8];
            a1.u = *(const uint4*)&Ap[(size_t)(m0 + 16 + m) * 128 + d0 + q * 8];
#pragma unroll
            for (int nf = 0; nf < 4; ++nf)
                bb[nf].u = *(const uint4*)&Bp[(size_t)(n0 + nf * 16 + m) * 128 + d0 + q * 8];
#pragma unroll
            for (int nf = 0; nf < 4; ++nf) {
                acc[0][nf] = __builtin_amdgcn_mfma_f32_16x16x32_bf16(a0.b, bb[nf].b, acc[0][nf], 0, 0, 0);
                acc[1][nf] = __builtin_amdgcn_mfma_f32_16x16x32_bf16(a1.b, bb[nf].b, acc[1][nf], 0, 0, 0);
            }
        }
    }

    // epilogue: C row = re = m0 + mf*16 + q*4 + reg, col = i = n0 + nf*16 + (lane&15)
    const int col = m;
#pragma unroll
    for (int mf = 0; mf < 2; ++mf) {
#pragma unroll
        for (int reg = 0; reg < 4; ++reg) {
            int re = m0 + mf * 16 + q * 4 + reg;
            float bv = bias[re];
            size_t rowoff = ((size_t)b * 768 + re) * 1024;
#pragma unroll
            for (int nf = 0; nf < 4; ++nf) {
                int i = n0 + nf * 16 + col;
                BmatT[rowoff + i] = f2bf(acc[mf][nf][reg] + bv);
            }
        }
    }
}

// ---------------------------------------------------------------------------
// Kernel 3: out[b,j,:] = sym[b,j,:] + sum_r sum_i (rel[j][i]==r) * BmatT[b][r][:,i]
// Block: 512 thr = 8 waves (wj 0..1 x we 0..3), block tile 32j x 128e, wave 16j x 32e.
// Phase 0: pos -> LDS; classify rel codes u8 [32 j][1032 pad] (sentinel 6 on diag).
// Phase 1: per (r, k-step): synthesize A mask-frag from 8 codes (ds_read_b64),
//          2 B-frags direct from L2, 2 MFMAs. Grid 256 (b = blk&7 for XCD locality).
// ---------------------------------------------------------------------------
#define RELPITCH 1032
__global__ __launch_bounds__(512)
void agg_mfma(const float* __restrict__ sym, const float* __restrict__ pos,
              const uint16_t* __restrict__ BmatT, float* __restrict__ out) {
    __shared__ float2 posS[1024];
    __shared__ uint8_t rel[32 * RELPITCH];

    const int x = blockIdx.x;
    const int b = x & 7;
    const int jt = x >> 3;       // 0..31
    const int j0 = jt * 32;
    const int tid = threadIdx.x;

    // ---- phase 0a: stage positions ----
    const float2* pos2 = (const float2*)pos + (size_t)b * 1024;
    posS[tid] = pos2[tid];
    posS[tid + 512] = pos2[tid + 512];
    __syncthreads();

    // ---- phase 0b: classify 32 j x 1024 i ----
    {
        const int m = tid >> 4, ic = tid & 15;
        const int j = j0 + m;
        const float2 pj = posS[j];
        uint32_t* dst = (uint32_t*)&rel[m * RELPITCH + ic * 64];
#pragma unroll 4
        for (int s = 0; s < 16; ++s) {
            uint32_t word = 0;
#pragma unroll
            for (int qq = 0; qq < 4; ++qq) {
                int i = ic * 64 + s * 4 + qq;
                float2 pi = posS[i];
                float dx = pj.x - pi.x;
                float dy = pj.y - pi.y;
                int r = (dy > 0.5f) ? 0
                      : (dy < -0.5f) ? 1
                      : (dx < -0.5f) ? 2
                      : (dx > 0.5f)  ? 3
                      : (fabsf(dx) < 0.3f && fabsf(dy) < 0.3f) ? 4
                      : 5;
                if (i == j) r = 6;  // diagonal: excluded (never matches r<6)
                word |= ((uint32_t)r) << (8 * qq);
            }
            dst[s] = word;
        }
    }
    __syncthreads();

    // ---- phase 1: masked MFMA GEMM ----
    const int w = tid >> 6, lane = tid & 63;
    const int wj = w >> 2, we = w & 3;
    const int m = lane & 15, q = lane >> 4;

    const uint8_t* relrow = &rel[(wj * 16 + m) * RELPITCH + q * 8];
    // B-frag lane row: e = we*32 + nf*16 + (lane&15); k-offset q*8 folded in.
    const uint16_t* Bbase = BmatT + ((size_t)b * 768 + we * 32 + m) * 1024 + q * 8;

    f32x4 acc0 = {0.f, 0.f, 0.f, 0.f}, acc1 = {0.f, 0.f, 0.f, 0.f};

    for (int r = 0; r < 6; ++r) {
        const uint16_t* B0 = Bbase + (size_t)r * 131072;   // +r*128 rows
        const uint16_t* B1 = B0 + 16 * 1024;               // nf=1: e+16
        const uint32_t rr = (uint32_t)r * 0x01010101u;
#pragma unroll 4
        for (int ks = 0; ks < 32; ++ks) {
            const int i0 = ks * 32;
            uint2 cw = *(const uint2*)(relrow + i0);
            uint32_t x0 = cw.x ^ rr, x1 = cw.y ^ rr;   // zero byte == match
            U4B a;
            a.u.x = (((x0 & 0x000000FFu) == 0u) ? 0x3F80u : 0u) |
                    (((x0 & 0x0000FF00u) == 0u) ? 0x3F800000u : 0u);
            a.u.y = (((x0 & 0x00FF0000u) == 0u) ? 0x3F80u : 0u) |
                    (((x0 & 0xFF000000u) == 0u) ? 0x3F800000u : 0u);
            a.u.z = (((x1 & 0x000000FFu) == 0u) ? 0x3F80u : 0u) |
                    (((x1 & 0x0000FF00u) == 0u) ? 0x3F800000u : 0u);
            a.u.w = (((x1 & 0x00FF0000u) == 0u) ? 0x3F80u : 0u) |
                    (((x1 & 0xFF000000u) == 0u) ? 0x3F800000u : 0u);
            U4B b0, b1;
            b0.u = *(const uint4*)(B0 + i0);
            b1.u = *(const uint4*)(B1 + i0);
            acc0 = __builtin_amdgcn_mfma_f32_16x16x32_bf16(a.b, b0.b, acc0, 0, 0, 0);
            acc1 = __builtin_amdgcn_mfma_f32_16x16x32_bf16(a.b, b1.b, acc1, 0, 0, 0);
        }
    }

    // ---- epilogue: row = j-local = q*4+reg, col = e-local = lane&15 ----
    const int jbase = j0 + wj * 16 + q * 4;
    const int ebase = we * 32 + m;
#pragma unroll
    for (int reg = 0; reg < 4; ++reg) {
        size_t o = ((size_t)(b * 1024 + jbase + reg)) * 128 + ebase;
        out[o]      = sym[o]      + acc0[reg];
        out[o + 16] = sym[o + 16] + acc1[reg];
    }
}

extern "C" void kernel_launch(void* const* d_in, const int* in_sizes, int n_in,
                              void* d_out, int out_size, void* d_ws, size_t ws_size,
                              hipStream_t stream) {
    const float* symbols   = (const float*)d_in[0];  // [8,1024,128]
    const float* positions = (const float*)d_in[1];  // [8,1024,2]
    const float* W         = (const float*)d_in[2];  // [6,128,128]
    const float* bias      = (const float*)d_in[3];  // [6,128]
    float* out             = (float*)d_out;          // [8,1024,128]

    char* ws = (char*)d_ws;
    uint16_t* BmatT = (uint16_t*)ws;                   // 12,582,912 B: [8][768][1024] bf16
    uint16_t* Xh    = (uint16_t*)(ws + 12582912);      // 2,097,152 B
    uint16_t* Xl    = (uint16_t*)(ws + 14680064);      // 2,097,152 B
    uint16_t* Wh    = (uint16_t*)(ws + 16777216);      //   196,608 B
    uint16_t* Wl    = (uint16_t*)(ws + 16973824);      //   196,608 B  (end ~17.2 MB)

    split_kernel<<<1120, 256, 0, stream>>>(symbols, W, Xh, Xl, Wh, Wl);
    bmat_mfma<<<768, 256, 0, stream>>>(Wh, Wl, Xh, Xl, bias, BmatT);
    agg_mfma<<<256, 512, 0, stream>>>(symbols, positions, BmatT, out);
}

// Round 4
// 173.749 us; speedup vs baseline: 2.3710x; 1.0607x over previous
//
#include <hip/hip_runtime.h>
#include <stdint.h>

// out[b,j,:] = sym[b,j,:] + sum_{i!=j} (sym[b,i,:] @ W[rel(i,j)].T + bias[rel(i,j)])
// B=8, N=1024, D=128, 6 relations.
//
// 1. split_kernel: X,W fp32 -> (hi,lo) bf16 pairs (split-bf16 ~fp32 accuracy)
// 2. bmat_mfma:    BmatT[b][r*128+e][i] = WhXh + WhXl + WlXh + bias   (bf16, i-contig)
//                  LDS-staged fragments (fixes R3's 256B-stride scatter loads)
// 3. agg_mfma:     6 masked GEMMs, one-hot byte codes in LDS, masks synthesized in
//                  registers (zero-byte trick + v_perm); K-split over waves for 2x occupancy.

typedef __attribute__((ext_vector_type(8))) short bf16x8;
typedef __attribute__((ext_vector_type(4))) float f32x4;
union U4B { uint4 u; bf16x8 b; };

__device__ __forceinline__ uint16_t f2bf(float f) {
    union { float f; uint32_t u; } v; v.f = f;
    uint32_t u = v.u;
    uint32_t r = (u + 0x7FFFu + ((u >> 16) & 1u)) >> 16;  // RNE
    return (uint16_t)r;
}
__device__ __forceinline__ float bf2f(uint16_t h) {
    union { uint32_t u; float f; } v; v.u = ((uint32_t)h) << 16; return v.f;
}

// ---------------------------------------------------------------------------
// Kernel 1: split fp32 -> (hi, lo) bf16.  X: 262144 float4, W: 24576 float4.
// ---------------------------------------------------------------------------
__global__ __launch_bounds__(256)
void split_kernel(const float* __restrict__ X, const float* __restrict__ W,
                  uint16_t* __restrict__ Xh, uint16_t* __restrict__ Xl,
                  uint16_t* __restrict__ Wh, uint16_t* __restrict__ Wl) {
    int idx = blockIdx.x * 256 + threadIdx.x;
    const float* src; uint16_t* dh; uint16_t* dl; int base;
    if (idx < 262144) { src = X; dh = Xh; dl = Xl; base = idx; }
    else {
        base = idx - 262144;
        if (base >= 24576) return;
        src = W; dh = Wh; dl = Wl;
    }
    float4 v = ((const float4*)src)[base];
    uint16_t h0 = f2bf(v.x), h1 = f2bf(v.y), h2 = f2bf(v.z), h3 = f2bf(v.w);
    uint16_t l0 = f2bf(v.x - bf2f(h0)), l1 = f2bf(v.y - bf2f(h1));
    uint16_t l2 = f2bf(v.z - bf2f(h2)), l3 = f2bf(v.w - bf2f(h3));
    uint2 ph = { (uint32_t)h0 | ((uint32_t)h1 << 16), (uint32_t)h2 | ((uint32_t)h3 << 16) };
    uint2 pl = { (uint32_t)l0 | ((uint32_t)l1 << 16), (uint32_t)l2 | ((uint32_t)l3 << 16) };
    *(uint2*)&dh[(size_t)base * 4] = ph;
    *(uint2*)&dl[(size_t)base * 4] = pl;
}

// ---------------------------------------------------------------------------
// Kernel 2: BmatT[(b*768+re)*1024 + i] = bf16(sum_d W[re,d]*X[b,i,d] + bias[re])
// Block 256 thr = 4 waves. C-tile 32re x 256i (wave: 32re x 64i). K = 3c x 128d.
// LDS single-buffer per 32-d chunk; pitch 40 hw -> conflict-free b128 frag reads.
// Grid 768 = 8b x 24ret x 4it  (b in low bits: per-XCD L2 locality).
// ---------------------------------------------------------------------------
#define XP 40   // halfword pitch (80 B): 16B-aligned rows, (5n+q)%8 uniform banks

__global__ __launch_bounds__(256)
void bmat_mfma(const uint16_t* __restrict__ Wh, const uint16_t* __restrict__ Wl,
               const uint16_t* __restrict__ Xh, const uint16_t* __restrict__ Xl,
               const float* __restrict__ bias, uint16_t* __restrict__ BmatT) {
    const int x = blockIdx.x;
    const int b  = x & 7;
    const int t6 = x >> 3;          // 0..95
    const int ret = t6 % 24;        // re tile (32 wide)
    const int it  = t6 / 24;        // i tile (256 wide)
    const int m0 = ret * 32;
    const int n0 = it * 256;
    const int tid = threadIdx.x;
    const int w = tid >> 6, lane = tid & 63;
    const int m = lane & 15, q = lane >> 4;

    __shared__ uint16_t XhS[256 * XP];   // 20 KB
    __shared__ uint16_t XlS[256 * XP];   // 20 KB
    __shared__ uint16_t WhS[32 * XP];    // 2.5 KB
    __shared__ uint16_t WlS[32 * XP];    // 2.5 KB

    const uint16_t* Xhb = Xh + ((size_t)(b * 1024 + n0) << 7);
    const uint16_t* Xlb = Xl + ((size_t)(b * 1024 + n0) << 7);

    f32x4 acc[2][4];
#pragma unroll
    for (int a = 0; a < 2; ++a)
#pragma unroll
        for (int n = 0; n < 4; ++n) acc[a][n] = (f32x4){0.f, 0.f, 0.f, 0.f};

    for (int d0 = 0; d0 < 128; d0 += 32) {
        // stage X h/l: 1024 uint4 per buffer, 4 lanes x 16B cover one i-row's 64B
#pragma unroll
        for (int s = 0; s < 4; ++s) {
            int f = s * 256 + tid;
            int il = f >> 2, dc = f & 3;
            uint4 vh = *(const uint4*)&Xhb[(size_t)il * 128 + d0 + dc * 8];
            uint4 vl = *(const uint4*)&Xlb[(size_t)il * 128 + d0 + dc * 8];
            *(uint4*)&XhS[il * XP + dc * 8] = vh;
            *(uint4*)&XlS[il * XP + dc * 8] = vl;
        }
        // stage W h/l: 32re x 32d each; threads 0..127 -> Wh, 128..255 -> Wl
        {
            int tt = tid & 127;
            int re = tt >> 2, dc = tt & 3;
            const uint16_t* srcp = (tid < 128) ? Wh : Wl;
            uint16_t* dstp = (tid < 128) ? WhS : WlS;
            uint4 v = *(const uint4*)&srcp[(size_t)(m0 + re) * 128 + d0 + dc * 8];
            *(uint4*)&dstp[re * XP + dc * 8] = v;
        }
        __syncthreads();

#pragma unroll
        for (int c = 0; c < 3; ++c) {
            const uint16_t* AS = (c < 2) ? WhS : WlS;
            const uint16_t* BS = (c == 1) ? XlS : XhS;
            U4B af[2], bfr[4];
#pragma unroll
            for (int mf = 0; mf < 2; ++mf)
                af[mf].u = *(const uint4*)&AS[(mf * 16 + m) * XP + q * 8];
#pragma unroll
            for (int nf = 0; nf < 4; ++nf)
                bfr[nf].u = *(const uint4*)&BS[(w * 64 + nf * 16 + m) * XP + q * 8];
#pragma unroll
            for (int mf = 0; mf < 2; ++mf)
#pragma unroll
                for (int nf = 0; nf < 4; ++nf)
                    acc[mf][nf] = __builtin_amdgcn_mfma_f32_16x16x32_bf16(
                        af[mf].b, bfr[nf].b, acc[mf][nf], 0, 0, 0);
        }
        __syncthreads();
    }

    // epilogue: C row = re (q*4+reg), col = i (lane&15)
    const int iw = n0 + w * 64;
#pragma unroll
    for (int mf = 0; mf < 2; ++mf) {
#pragma unroll
        for (int reg = 0; reg < 4; ++reg) {
            int re = m0 + mf * 16 + q * 4 + reg;
            float bv = bias[re];
            size_t rowo = ((size_t)(b * 768 + re)) << 10;
#pragma unroll
            for (int nf = 0; nf < 4; ++nf) {
                int i = iw + nf * 16 + m;
                BmatT[rowo + i] = f2bf(acc[mf][nf][reg] + bv);
            }
        }
    }
}

// ---------------------------------------------------------------------------
// Kernel 3: out[b,j,:] = sym[b,j,:] + sum_r sum_i onehot_r[j][i] * BmatT[b][r][:,i]
// Grid 512 = 8b x 64jt (16 j each). Block 512 thr = 8 waves = (we 0..3: 32e) x
// (kw 0..1: r-halves). K-split partials reduced via LDS. Codes: one-hot bytes
// (1<<r, 0 on diagonal), dword pitch 257 (odd -> mixed-parity banks).
// ---------------------------------------------------------------------------
#define RELDW 257

__global__ __launch_bounds__(512)
void agg_mfma(const float* __restrict__ sym, const float* __restrict__ pos,
              const uint16_t* __restrict__ BmatT, float* __restrict__ out) {
    __shared__ float2 posS[1024];           // 8 KB
    __shared__ uint32_t rel32[16 * RELDW];  // 16.4 KB
    __shared__ float red[8 * 256];          // 8 KB (k-split partials)

    const int x = blockIdx.x;
    const int b = x & 7;                    // per-XCD L2 locality for BmatT[b]
    const int jt = x >> 3;                  // 0..63
    const int j0 = jt * 16;
    const int tid = threadIdx.x;

    // ---- stage positions ----
    const float2* pos2 = (const float2*)pos + ((size_t)b << 10);
    posS[tid] = pos2[tid];
    posS[tid + 512] = pos2[tid + 512];
    __syncthreads();

    // ---- classify: thread (m=tid&15 -> j, grp=tid>>4 -> 32 i's) ----
    {
        const int m = tid & 15, grp = tid >> 4;
        const int j = j0 + m;
        const float2 pj = posS[j];
        uint32_t* dst = &rel32[m * RELDW + grp * 8];
#pragma unroll
        for (int s = 0; s < 8; ++s) {
            uint32_t word = 0;
#pragma unroll
            for (int qq = 0; qq < 4; ++qq) {
                int i = grp * 32 + s * 4 + qq;
                float2 pi = posS[i];
                float dx = pj.x - pi.x;
                float dy = pj.y - pi.y;
                // faithful priority chain of _get_relation_type
                int r = (dy > 0.5f) ? 0
                      : (dy < -0.5f) ? 1
                      : (dx < -0.5f) ? 2
                      : (dx > 0.5f)  ? 3
                      : (fabsf(dx) < 0.3f && fabsf(dy) < 0.3f) ? 4
                      : 5;
                uint32_t oh = (i == j) ? 0u : (1u << r);  // one-hot; diag excluded
                word |= oh << (8 * qq);
            }
            dst[s] = word;
        }
    }
    __syncthreads();

    // ---- masked MFMA GEMM, ks-outer / r-inner ----
    const int w = tid >> 6, lane = tid & 63;
    const int we = w & 3, kw = w >> 2;
    const int m = lane & 15, q = lane >> 4;

    const uint32_t* crow = &rel32[m * RELDW + q * 2];
    const uint16_t* Bw = BmatT + (((size_t)(b * 768 + kw * 384 + we * 32 + m)) << 10) + q * 8;

    f32x4 acc0 = {0.f, 0.f, 0.f, 0.f}, acc1 = {0.f, 0.f, 0.f, 0.f};

    for (int ks = 0; ks < 32; ++ks) {
        uint32_t c0 = crow[ks * 8];
        uint32_t c1 = crow[ks * 8 + 1];
        const size_t io = (size_t)ks * 32;
#pragma unroll
        for (int rr = 0; rr < 3; ++rr) {
            const uint32_t rm = 0x01010101u << (kw * 3 + rr);
            // one-hot match -> 0xFF per byte (no cross-byte carries: bytes <= 0x20+0x7F)
            uint32_t z0 = (c0 & rm) + 0x7F7F7F7Fu;
            uint32_t z1 = (c1 & rm) + 0x7F7F7F7Fu;
            uint32_t y0 = z0 & 0x80808080u;
            uint32_t y1 = z1 & 0x80808080u;
            uint32_t f0 = y0 | (y0 - (y0 >> 7));
            uint32_t f1 = y1 | (y1 - (y1 >> 7));
            U4B a;
            a.u.x = __builtin_amdgcn_perm(f0, f0, 0x01010000u) & 0x3F803F80u;
            a.u.y = __builtin_amdgcn_perm(f0, f0, 0x03030202u) & 0x3F803F80u;
            a.u.z = __builtin_amdgcn_perm(f1, f1, 0x01010000u) & 0x3F803F80u;
            a.u.w = __builtin_amdgcn_perm(f1, f1, 0x03030202u) & 0x3F803F80u;
            U4B b0, b1;
            b0.u = *(const uint4*)(Bw + rr * 131072 + io);
            b1.u = *(const uint4*)(Bw + rr * 131072 + 16384 + io);
            acc0 = __builtin_amdgcn_mfma_f32_16x16x32_bf16(a.b, b0.b, acc0, 0, 0, 0);
            acc1 = __builtin_amdgcn_mfma_f32_16x16x32_bf16(a.b, b1.b, acc1, 0, 0, 0);
        }
    }

    // ---- k-split reduce: kw1 -> LDS (bank-safe: index = k*256 + we*64 + lane) ----
    if (kw == 1) {
#pragma unroll
        for (int k = 0; k < 4; ++k) {
            red[k * 256 + we * 64 + lane]       = acc0[k];
            red[(k + 4) * 256 + we * 64 + lane] = acc1[k];
        }
    }
    __syncthreads();
    if (kw == 0) {
#pragma unroll
        for (int k = 0; k < 4; ++k) {
            acc0[k] += red[k * 256 + we * 64 + lane];
            acc1[k] += red[(k + 4) * 256 + we * 64 + lane];
        }
        // epilogue: C row = j-local (q*4+reg), col = e-local (lane&15)
        const int jb = j0 + q * 4;
        const int e0 = we * 32 + m;
#pragma unroll
        for (int reg = 0; reg < 4; ++reg) {
            size_t o = ((size_t)(b * 1024 + jb + reg) << 7) + e0;
            out[o]      = sym[o]      + acc0[reg];
            out[o + 16] = sym[o + 16] + acc1[reg];
        }
    }
}

extern "C" void kernel_launch(void* const* d_in, const int* in_sizes, int n_in,
                              void* d_out, int out_size, void* d_ws, size_t ws_size,
                              hipStream_t stream) {
    const float* symbols   = (const float*)d_in[0];  // [8,1024,128]
    const float* positions = (const float*)d_in[1];  // [8,1024,2]
    const float* W         = (const float*)d_in[2];  // [6,128,128]
    const float* bias      = (const float*)d_in[3];  // [6,128]
    float* out             = (float*)d_out;          // [8,1024,128]

    char* ws = (char*)d_ws;
    uint16_t* BmatT = (uint16_t*)ws;                   // 12,582,912 B: [8][768][1024] bf16
    uint16_t* Xh    = (uint16_t*)(ws + 12582912);      // 2,097,152 B
    uint16_t* Xl    = (uint16_t*)(ws + 14680064);      // 2,097,152 B
    uint16_t* Wh    = (uint16_t*)(ws + 16777216);      //   196,608 B
    uint16_t* Wl    = (uint16_t*)(ws + 16973824);      //   196,608 B

    split_kernel<<<1120, 256, 0, stream>>>(symbols, W, Xh, Xl, Wh, Wl);
    bmat_mfma<<<768, 256, 0, stream>>>(Wh, Wl, Xh, Xl, bias, BmatT);
    agg_mfma<<<512, 512, 0, stream>>>(symbols, positions, BmatT, out);
}

// Round 5
// 141.896 us; speedup vs baseline: 2.9032x; 1.2245x over previous
//
#include <hip/hip_runtime.h>
#include <stdint.h>

// out[b,j,:] = sym[b,j,:] + sum_{i!=j} (sym[b,i,:] @ W[rel(i,j)].T + bias[rel(i,j)])
// B=8, N=1024, D=128, 6 relations.
//
// 1. split_kernel: X,W fp32 -> (hi,lo) bf16 pairs (split-bf16 ~fp32 accuracy)
// 2. bmat_mfma:    BmatT[b][r*128+e][i] = WhXh + WhXl + WlXh + bias (bf16, i-contig)
//                  NEW: C-tile routed through LDS -> coalesced dwordx4 stores
//                  (R4's 2-B scattered stores were line-transaction-bound).
// 3. agg_mfma:     6 masked GEMMs; NEW: B-tiles double-buffered through LDS
//                  (R4's direct global frags = 64 lines/instr, TA-bound).

typedef __attribute__((ext_vector_type(8))) short bf16x8;
typedef __attribute__((ext_vector_type(4))) float f32x4;
union U4B { uint4 u; bf16x8 b; };

__device__ __forceinline__ uint16_t f2bf(float f) {
    union { float f; uint32_t u; } v; v.f = f;
    uint32_t u = v.u;
    uint32_t r = (u + 0x7FFFu + ((u >> 16) & 1u)) >> 16;  // RNE
    return (uint16_t)r;
}
__device__ __forceinline__ float bf2f(uint16_t h) {
    union { uint32_t u; float f; } v; v.u = ((uint32_t)h) << 16; return v.f;
}

// ---------------------------------------------------------------------------
// Kernel 1: split fp32 -> (hi, lo) bf16.  X: 262144 float4, W: 24576 float4.
// ---------------------------------------------------------------------------
__global__ __launch_bounds__(256)
void split_kernel(const float* __restrict__ X, const float* __restrict__ W,
                  uint16_t* __restrict__ Xh, uint16_t* __restrict__ Xl,
                  uint16_t* __restrict__ Wh, uint16_t* __restrict__ Wl) {
    int idx = blockIdx.x * 256 + threadIdx.x;
    const float* src; uint16_t* dh; uint16_t* dl; int base;
    if (idx < 262144) { src = X; dh = Xh; dl = Xl; base = idx; }
    else {
        base = idx - 262144;
        if (base >= 24576) return;
        src = W; dh = Wh; dl = Wl;
    }
    float4 v = ((const float4*)src)[base];
    uint16_t h0 = f2bf(v.x), h1 = f2bf(v.y), h2 = f2bf(v.z), h3 = f2bf(v.w);
    uint16_t l0 = f2bf(v.x - bf2f(h0)), l1 = f2bf(v.y - bf2f(h1));
    uint16_t l2 = f2bf(v.z - bf2f(h2)), l3 = f2bf(v.w - bf2f(h3));
    uint2 ph = { (uint32_t)h0 | ((uint32_t)h1 << 16), (uint32_t)h2 | ((uint32_t)h3 << 16) };
    uint2 pl = { (uint32_t)l0 | ((uint32_t)l1 << 16), (uint32_t)l2 | ((uint32_t)l3 << 16) };
    *(uint2*)&dh[(size_t)base * 4] = ph;
    *(uint2*)&dl[(size_t)base * 4] = pl;
}

// ---------------------------------------------------------------------------
// Kernel 2: BmatT[(b*768+re)*1024 + i] = bf16(sum_d W[re,d]*X[b,i,d] + bias[re])
// Block 256 thr = 4 waves. C-tile 32re x 256i (wave: 32re x 64i). K = 3c x 128d.
// Grid 768 = 8b x 24ret x 4it. LDS pitch 40hw frag staging + LDS C-epilogue.
// ---------------------------------------------------------------------------
#define XP 40   // halfword pitch for staged frags
#define CP 264  // halfword pitch for C-epilogue tile (32 x 264)

__global__ __launch_bounds__(256)
void bmat_mfma(const uint16_t* __restrict__ Wh, const uint16_t* __restrict__ Wl,
               const uint16_t* __restrict__ Xh, const uint16_t* __restrict__ Xl,
               const float* __restrict__ bias, uint16_t* __restrict__ BmatT) {
    const int x = blockIdx.x;
    const int b  = x & 7;
    const int t6 = x >> 3;          // 0..95
    const int ret = t6 % 24;        // re tile (32 wide)
    const int it  = t6 / 24;        // i tile (256 wide)
    const int m0 = ret * 32;
    const int n0 = it * 256;
    const int tid = threadIdx.x;
    const int w = tid >> 6, lane = tid & 63;
    const int m = lane & 15, q = lane >> 4;

    __shared__ __align__(16) char smem[46080];
    uint16_t* XhS = (uint16_t*)smem;             // 256*40*2 = 20480 B
    uint16_t* XlS = (uint16_t*)(smem + 20480);   // 20480 B
    uint16_t* WhS = (uint16_t*)(smem + 40960);   // 2560 B
    uint16_t* WlS = (uint16_t*)(smem + 43520);   // 2560 B

    const uint16_t* Xhb = Xh + ((size_t)(b * 1024 + n0) << 7);
    const uint16_t* Xlb = Xl + ((size_t)(b * 1024 + n0) << 7);

    f32x4 acc[2][4];
#pragma unroll
    for (int a = 0; a < 2; ++a)
#pragma unroll
        for (int n = 0; n < 4; ++n) acc[a][n] = (f32x4){0.f, 0.f, 0.f, 0.f};

    for (int d0 = 0; d0 < 128; d0 += 32) {
#pragma unroll
        for (int s = 0; s < 4; ++s) {
            int f = s * 256 + tid;
            int il = f >> 2, dc = f & 3;
            uint4 vh = *(const uint4*)&Xhb[(size_t)il * 128 + d0 + dc * 8];
            uint4 vl = *(const uint4*)&Xlb[(size_t)il * 128 + d0 + dc * 8];
            *(uint4*)&XhS[il * XP + dc * 8] = vh;
            *(uint4*)&XlS[il * XP + dc * 8] = vl;
        }
        {
            int tt = tid & 127;
            int re = tt >> 2, dc = tt & 3;
            const uint16_t* srcp = (tid < 128) ? Wh : Wl;
            uint16_t* dstp = (tid < 128) ? WhS : WlS;
            uint4 v = *(const uint4*)&srcp[(size_t)(m0 + re) * 128 + d0 + dc * 8];
            *(uint4*)&dstp[re * XP + dc * 8] = v;
        }
        __syncthreads();

#pragma unroll
        for (int c = 0; c < 3; ++c) {
            const uint16_t* AS = (c < 2) ? WhS : WlS;
            const uint16_t* BS = (c == 1) ? XlS : XhS;
            U4B af[2], bfr[4];
#pragma unroll
            for (int mf = 0; mf < 2; ++mf)
                af[mf].u = *(const uint4*)&AS[(mf * 16 + m) * XP + q * 8];
#pragma unroll
            for (int nf = 0; nf < 4; ++nf)
                bfr[nf].u = *(const uint4*)&BS[(w * 64 + nf * 16 + m) * XP + q * 8];
#pragma unroll
            for (int mf = 0; mf < 2; ++mf)
#pragma unroll
                for (int nf = 0; nf < 4; ++nf)
                    acc[mf][nf] = __builtin_amdgcn_mfma_f32_16x16x32_bf16(
                        af[mf].b, bfr[nf].b, acc[mf][nf], 0, 0, 0);
        }
        __syncthreads();
    }

    // ---- epilogue via LDS (reuse smem): coalesced dwordx4 stores ----
    uint16_t* CS = (uint16_t*)smem;   // 32 x CP hw = 16896 B
#pragma unroll
    for (int mf = 0; mf < 2; ++mf)
#pragma unroll
        for (int reg = 0; reg < 4; ++reg) {
            int rl = mf * 16 + q * 4 + reg;
            float bv = bias[m0 + rl];
#pragma unroll
            for (int nf = 0; nf < 4; ++nf)
                CS[rl * CP + w * 64 + nf * 16 + m] = f2bf(acc[mf][nf][reg] + bv);
        }
    __syncthreads();
#pragma unroll
    for (int s = 0; s < 4; ++s) {
        int idx = s * 256 + tid;
        int row = idx >> 5, c16 = idx & 31;
        uint4 v = *(const uint4*)&CS[row * CP + c16 * 8];
        *(uint4*)&BmatT[(((size_t)(b * 768 + m0 + row)) << 10) + n0 + c16 * 8] = v;
    }
}

// ---------------------------------------------------------------------------
// Kernel 3: out[b,j,:] = sym[b,j,:] + sum_r sum_i onehot_r[j][i] * BmatT[b][r][:,i]
// Grid 512 = 8b x 64jt (16 j). Block 512 thr = 8 waves (wave = 16e group).
// 96 chunks (6r x 16 i-blocks of 64): stage B[128e][64i] in double-buffered LDS
// (pitch 72 hw; staging rows permuted {0,2,4,6,1,3,5,7} so write groups spread
// -> both ds_write_b128 and ds_read_b128 are 2-way max). Masks synthesized in
// registers from one-hot LDS codes (dword pitch 258).
// ---------------------------------------------------------------------------
#define RELDW 258
#define BTP 72

__global__ __launch_bounds__(512)
void agg_mfma(const float* __restrict__ sym, const float* __restrict__ pos,
              const uint16_t* __restrict__ BmatT, float* __restrict__ out) {
    __shared__ float2 posS[1024];             // 8192 B
    __shared__ uint32_t rel32[16 * RELDW];    // 16512 B
    __shared__ uint16_t BT[2][128 * BTP];     // 36864 B   (total 61568 B)

    const int x = blockIdx.x;
    const int b = x & 7;                      // per-XCD L2 locality for BmatT[b]
    const int jt = x >> 3;                    // 0..63
    const int j0 = jt * 16;
    const int tid = threadIdx.x;

    // ---- stage positions ----
    const float2* pos2 = (const float2*)pos + ((size_t)b << 10);
    posS[tid] = pos2[tid];
    posS[tid + 512] = pos2[tid + 512];
    __syncthreads();

    // ---- classify 16 j x 1024 i -> one-hot bytes ----
    {
        const int mm = tid & 15, grp = tid >> 4;
        const int j = j0 + mm;
        const float2 pj = posS[j];
        uint32_t* dst = &rel32[mm * RELDW + grp * 8];
#pragma unroll
        for (int s = 0; s < 8; ++s) {
            uint32_t word = 0;
#pragma unroll
            for (int qq = 0; qq < 4; ++qq) {
                int i = grp * 32 + s * 4 + qq;
                float2 pi = posS[i];
                float dx = pj.x - pi.x;
                float dy = pj.y - pi.y;
                // faithful priority chain of _get_relation_type
                int r = (dy > 0.5f) ? 0
                      : (dy < -0.5f) ? 1
                      : (dx < -0.5f) ? 2
                      : (dx > 0.5f)  ? 3
                      : (fabsf(dx) < 0.3f && fabsf(dy) < 0.3f) ? 4
                      : 5;
                uint32_t oh = (i == j) ? 0u : (1u << r);
                word |= oh << (8 * qq);
            }
            dst[s] = word;
        }
    }

    // ---- staging thread map (row-permuted for LDS write bank spread) ----
    const int t4 = tid >> 2;
    const int strow = ((t4 & 3) << 1) | ((t4 >> 2) & 1) | ((t4 >> 3) << 3);
    const int s0 = tid & 3;                   // covers slots s0 and s0+4
    const uint16_t* gB = BmatT + (((size_t)b * 768) << 10);

    // prime chunk 0 (r=0, i0=0)
    {
        const uint16_t* gp = gB + ((size_t)strow << 10);
        uint4 a0 = *(const uint4*)(gp + s0 * 8);
        uint4 a1 = *(const uint4*)(gp + s0 * 8 + 32);
        uint16_t* d = &BT[0][strow * BTP + s0 * 8];
        *(uint4*)d = a0;
        *(uint4*)(d + 32) = a1;
    }
    __syncthreads();

    const int w = tid >> 6, lane = tid & 63;
    const int m = lane & 15, q = lane >> 4;
    const int codebase = m * RELDW + q * 2;

    f32x4 acc = {0.f, 0.f, 0.f, 0.f};

    for (int c = 0; c < 96; ++c) {
        // prefetch next chunk into registers
        uint4 p0, p1;
        const bool hasn = (c + 1 < 96);
        if (hasn) {
            const int cn = c + 1;
            const uint16_t* gp = gB + (((size_t)((cn >> 4) * 128 + strow)) << 10)
                                    + ((cn & 15) << 6);
            p0 = *(const uint4*)(gp + s0 * 8);
            p1 = *(const uint4*)(gp + s0 * 8 + 32);
        }
        // compute current chunk
        const int r = c >> 4;
        const uint32_t rm = 0x01010101u << r;
        const int cb = codebase + ((c & 15) << 4);
        const uint16_t* bt = &BT[c & 1][(w * 16 + m) * BTP + q * 8];
#pragma unroll
        for (int ks = 0; ks < 2; ++ks) {
            uint2 cw = *(const uint2*)&rel32[cb + ks * 8];
            uint32_t z0 = (cw.x & rm) + 0x7F7F7F7Fu;
            uint32_t z1 = (cw.y & rm) + 0x7F7F7F7Fu;
            uint32_t y0 = z0 & 0x80808080u;
            uint32_t y1 = z1 & 0x80808080u;
            uint32_t f0 = y0 | (y0 - (y0 >> 7));
            uint32_t f1 = y1 | (y1 - (y1 >> 7));
            U4B a;
            a.u.x = __builtin_amdgcn_perm(f0, f0, 0x01010000u) & 0x3F803F80u;
            a.u.y = __builtin_amdgcn_perm(f0, f0, 0x03030202u) & 0x3F803F80u;
            a.u.z = __builtin_amdgcn_perm(f1, f1, 0x01010000u) & 0x3F803F80u;
            a.u.w = __builtin_amdgcn_perm(f1, f1, 0x03030202u) & 0x3F803F80u;
            U4B bfr;
            bfr.u = *(const uint4*)(bt + ks * 32);
            acc = __builtin_amdgcn_mfma_f32_16x16x32_bf16(a.b, bfr.b, acc, 0, 0, 0);
        }
        // write prefetched chunk to the other buffer
        if (hasn) {
            uint16_t* d = &BT[(c + 1) & 1][strow * BTP + s0 * 8];
            *(uint4*)d = p0;
            *(uint4*)(d + 32) = p1;
        }
        __syncthreads();
    }

    // ---- epilogue: C row = j-local (q*4+reg), col = e = w*16 + (lane&15) ----
    const int jb = j0 + q * 4;
    const int e0 = w * 16 + m;
#pragma unroll
    for (int reg = 0; reg < 4; ++reg) {
        size_t o = (((size_t)(b * 1024 + jb + reg)) << 7) + e0;
        out[o] = sym[o] + acc[reg];
    }
}

extern "C" void kernel_launch(void* const* d_in, const int* in_sizes, int n_in,
                              void* d_out, int out_size, void* d_ws, size_t ws_size,
                              hipStream_t stream) {
    const float* symbols   = (const float*)d_in[0];  // [8,1024,128]
    const float* positions = (const float*)d_in[1];  // [8,1024,2]
    const float* W         = (const float*)d_in[2];  // [6,128,128]
    const float* bias      = (const float*)d_in[3];  // [6,128]
    float* out             = (float*)d_out;          // [8,1024,128]

    char* ws = (char*)d_ws;
    uint16_t* BmatT = (uint16_t*)ws;                   // 12,582,912 B: [8][768][1024] bf16
    uint16_t* Xh    = (uint16_t*)(ws + 12582912);      // 2,097,152 B
    uint16_t* Xl    = (uint16_t*)(ws + 14680064);      // 2,097,152 B
    uint16_t* Wh    = (uint16_t*)(ws + 16777216);      //   196,608 B
    uint16_t* Wl    = (uint16_t*)(ws + 16973824);      //   196,608 B

    split_kernel<<<1120, 256, 0, stream>>>(symbols, W, Xh, Xl, Wh, Wl);
    bmat_mfma<<<768, 256, 0, stream>>>(Wh, Wl, Xh, Xl, bias, BmatT);
    agg_mfma<<<512, 512, 0, stream>>>(symbols, positions, BmatT, out);
}

// Round 6
// 129.366 us; speedup vs baseline: 3.1844x; 1.0969x over previous
//
#include <hip/hip_runtime.h>
#include <stdint.h>

// out[b,j,:] = sym[b,j,:] + sum_{i!=j} (sym[b,i,:] @ W[rel(i,j)].T + bias[rel(i,j)])
// B=8, N=1024, D=128, 6 relations.
//
// Linearity rewrite:  agg[j] = sum_r (sum_{i!=j, rel=r} sym[i]) @ W[r].T + cnt_r(j)*bias[r]
//  1. prep: symT bf16 [8][128 e][1024 i] (transpose), Wt2 bf16 [128 e'][768 k]
//     where Wt2[e'][r*128+e] = W[r][e'][e].
//  2. fused: per (b, 16-j tile):
//     A) classify 16x1024 one-hot codes (+ packed popcount counts) into LDS;
//     B) step A: S_r[16j x 32e/wave] = mask_r @ symT, 8 chunks of 128 i,
//        symT chunk staged once in LDS and reused by all 6 r (masks synthesized
//        in registers from codes);
//     C) step B: C2 = S @ Wt2 (K=768, wave-K-split), S through LDS (bf16),
//        partials reduced in LDS; epilogue adds sym + cnt_r*bias.

typedef __attribute__((ext_vector_type(8))) short bf16x8;
typedef __attribute__((ext_vector_type(4))) float f32x4;
union U4B { uint4 u; bf16x8 b; };

__device__ __forceinline__ uint16_t f2bf(float f) {
    union { float f; uint32_t u; } v; v.f = f;
    uint32_t u = v.u;
    uint32_t r = (u + 0x7FFFu + ((u >> 16) & 1u)) >> 16;  // RNE
    return (uint16_t)r;
}

// ---------------------------------------------------------------------------
// prep: blocks 0..255: transpose X[b][i][e] fp32 -> symT[b][e][i] bf16 (64x64 tiles)
//       blocks 256..351: permute W[r][e'][e] fp32 -> Wt2[e'][r*128+e] bf16
// ---------------------------------------------------------------------------
__global__ __launch_bounds__(256)
void prep_kernel(const float* __restrict__ X, const float* __restrict__ W,
                 uint16_t* __restrict__ symT, uint16_t* __restrict__ Wt2) {
    const int blk = blockIdx.x, tid = threadIdx.x;
    if (blk < 256) {
        __shared__ float T[64 * 68];
        const int b = blk & 7, z = blk >> 3, it = z & 15, et = z >> 4;
        const int i0 = it * 64, e0 = et * 64;
        const float4* Xf = (const float4*)X;
#pragma unroll
        for (int s = 0; s < 4; ++s) {
            int il = s * 16 + (tid >> 4), e4 = tid & 15;
            float4 v = Xf[((size_t)b << 15) + (size_t)((i0 + il) << 5) + (e0 >> 2) + e4];
            *(float4*)&T[il * 68 + e4 * 4] = v;
        }
        __syncthreads();
#pragma unroll
        for (int s = 0; s < 4; ++s) {
            int el = s * 16 + (tid >> 4), il4 = tid & 15;
            uint16_t h0 = f2bf(T[(il4 * 4 + 0) * 68 + el]);
            uint16_t h1 = f2bf(T[(il4 * 4 + 1) * 68 + el]);
            uint16_t h2 = f2bf(T[(il4 * 4 + 2) * 68 + el]);
            uint16_t h3 = f2bf(T[(il4 * 4 + 3) * 68 + el]);
            uint2 pk = { (uint32_t)h0 | ((uint32_t)h1 << 16),
                         (uint32_t)h2 | ((uint32_t)h3 << 16) };
            *(uint2*)&symT[((size_t)b << 17) + ((size_t)(e0 + el) << 10) + i0 + il4 * 4] = pk;
        }
    } else {
        int g = (blk - 256) * 256 + tid;          // 0..24575
        float4 v = ((const float4*)W)[g];
        int r = g >> 12, rem = g & 4095, ep = rem >> 5, e4 = rem & 31;
        uint16_t h0 = f2bf(v.x), h1 = f2bf(v.y), h2 = f2bf(v.z), h3 = f2bf(v.w);
        uint2 pk = { (uint32_t)h0 | ((uint32_t)h1 << 16),
                     (uint32_t)h2 | ((uint32_t)h3 << 16) };
        *(uint2*)&Wt2[(size_t)ep * 768 + r * 128 + e4 * 4] = pk;
    }
}

// ---------------------------------------------------------------------------
// fused kernel: grid 512 = 8b x 64jt (16 j per block), 256 thr = 4 e-waves.
// ---------------------------------------------------------------------------
#define RELDW 258

__global__ __launch_bounds__(256)
void fused_kernel(const float* __restrict__ sym, const float* __restrict__ pos,
                  const uint16_t* __restrict__ symT, const uint16_t* __restrict__ Wt2,
                  const float* __restrict__ bias, float* __restrict__ out) {
    __shared__ __align__(16) char smem[76288];
    // z1 @0     : posS 8192 | symTS 128*136*2=34816 | SA 4*6*16*40*2=30720
    // z2 @34816 : rel32 16*258*4=16512 | partial 4*16*132*4=33792
    // z3 @68608 : cntP 16*16*8*2=4096 ; z4 @72704: cntF 16*8*4=512 ; z5 @73216: biasS 3072
    float2*   posS   = (float2*)smem;
    uint16_t* symTS  = (uint16_t*)smem;
    uint16_t* SA     = (uint16_t*)smem;
    uint32_t* rel32  = (uint32_t*)(smem + 34816);
    float*    partial= (float*)(smem + 34816);
    uint16_t* cntP   = (uint16_t*)(smem + 68608);
    float*    cntF   = (float*)(smem + 72704);
    float*    biasS  = (float*)(smem + 73216);

    const int blk = blockIdx.x;
    const int b = blk & 7, jt = blk >> 3, j0 = jt * 16;
    const int tid = threadIdx.x;
    const int w = tid >> 6, lane = tid & 63, m = lane & 15, q = lane >> 4;

    const uint16_t* symTb = symT + ((size_t)b << 17);

    // prefetch chunk 0 (registers only; latency hidden under classify)
    uint4 pf[8];
#pragma unroll
    for (int s = 0; s < 8; ++s) {
        int f = s * 256 + tid, e = f >> 4, seg = f & 15;
        pf[s] = *(const uint4*)&symTb[(e << 10) + seg * 8];
    }

    // ---- phase 0: stage pos + bias ----
    const float2* pos2 = (const float2*)pos + ((size_t)b << 10);
#pragma unroll
    for (int k = 0; k < 4; ++k) posS[tid + k * 256] = pos2[tid + k * 256];
#pragma unroll
    for (int k = 0; k < 3; ++k) biasS[tid + k * 256] = bias[tid + k * 256];
    __syncthreads();

    // ---- phase 1: classify (one-hot bytes) + packed popcount counts ----
    {
        const int mm = tid & 15, grp = tid >> 4;
        const int j = j0 + mm;
        const float2 pj = posS[j];
        uint32_t a0 = 0, a1 = 0, a2 = 0, a3 = 0, a4 = 0, a5 = 0;
        uint32_t* dst = &rel32[mm * RELDW + grp * 16];
#pragma unroll
        for (int s = 0; s < 16; ++s) {
            uint32_t word = 0;
#pragma unroll
            for (int qq = 0; qq < 4; ++qq) {
                int i = grp * 64 + s * 4 + qq;
                float2 pi = posS[i];
                float dx = pj.x - pi.x, dy = pj.y - pi.y;
                // faithful priority chain of _get_relation_type
                int r = (dy > 0.5f) ? 0
                      : (dy < -0.5f) ? 1
                      : (dx < -0.5f) ? 2
                      : (dx > 0.5f)  ? 3
                      : (fabsf(dx) < 0.3f && fabsf(dy) < 0.3f) ? 4
                      : 5;
                uint32_t oh = (i == j) ? 0u : (1u << r);
                word |= oh << (8 * qq);
            }
            dst[s] = word;
            a0 += word & 0x01010101u;
            a1 += (word >> 1) & 0x01010101u;
            a2 += (word >> 2) & 0x01010101u;
            a3 += (word >> 3) & 0x01010101u;
            a4 += (word >> 4) & 0x01010101u;
            a5 += (word >> 5) & 0x01010101u;
        }
        uint16_t* cp = &cntP[(mm * 16 + grp) * 8];
        cp[0] = (uint16_t)((a0 * 0x01010101u) >> 24);
        cp[1] = (uint16_t)((a1 * 0x01010101u) >> 24);
        cp[2] = (uint16_t)((a2 * 0x01010101u) >> 24);
        cp[3] = (uint16_t)((a3 * 0x01010101u) >> 24);
        cp[4] = (uint16_t)((a4 * 0x01010101u) >> 24);
        cp[5] = (uint16_t)((a5 * 0x01010101u) >> 24);
    }
    __syncthreads();
    if (tid < 96) {   // cnt reduce: cntF[j][r]
        int j2 = tid / 6, r2 = tid - j2 * 6;
        int s = 0;
#pragma unroll
        for (int g = 0; g < 16; ++g) s += cntP[(j2 * 16 + g) * 8 + r2];
        cntF[j2 * 8 + r2] = (float)s;
    }
    // (cntF consumed only after later barriers)

    // ---- phase 2: step A — 8 chunks of 128 i ----
    f32x4 acc[6][2];
#pragma unroll
    for (int r = 0; r < 6; ++r)
#pragma unroll
        for (int ef = 0; ef < 2; ++ef) acc[r][ef] = (f32x4){0.f, 0.f, 0.f, 0.f};

    for (int c = 0; c < 8; ++c) {
#pragma unroll
        for (int s = 0; s < 8; ++s) {
            int f = s * 256 + tid, e = f >> 4, seg = f & 15;
            *(uint4*)&symTS[e * 136 + seg * 8] = pf[s];
        }
        __syncthreads();
        if (c < 7) {
#pragma unroll
            for (int s = 0; s < 8; ++s) {
                int f = s * 256 + tid, e = f >> 4, seg = f & 15;
                pf[s] = *(const uint4*)&symTb[(e << 10) + (c + 1) * 128 + seg * 8];
            }
        }
        const uint16_t* bt0 = &symTS[(w * 32 + m) * 136];
        const uint16_t* bt1 = &symTS[(w * 32 + 16 + m) * 136];
        const uint32_t* cr = &rel32[m * RELDW + c * 32 + q * 2];
#pragma unroll
        for (int ks = 0; ks < 4; ++ks) {
            U4B bf0, bf1;
            bf0.u = *(const uint4*)(bt0 + ks * 32 + q * 8);
            bf1.u = *(const uint4*)(bt1 + ks * 32 + q * 8);
            uint2 cw = *(const uint2*)(cr + ks * 8);
#pragma unroll
            for (int r = 0; r < 6; ++r) {
                const uint32_t rm = 0x01010101u << r;
                uint32_t z0 = (cw.x & rm) + 0x7F7F7F7Fu;
                uint32_t z1 = (cw.y & rm) + 0x7F7F7F7Fu;
                uint32_t y0 = z0 & 0x80808080u, y1 = z1 & 0x80808080u;
                uint32_t f0 = y0 | (y0 - (y0 >> 7));
                uint32_t f1 = y1 | (y1 - (y1 >> 7));
                U4B a;
                a.u.x = __builtin_amdgcn_perm(f0, f0, 0x01010000u) & 0x3F803F80u;
                a.u.y = __builtin_amdgcn_perm(f0, f0, 0x03030202u) & 0x3F803F80u;
                a.u.z = __builtin_amdgcn_perm(f1, f1, 0x01010000u) & 0x3F803F80u;
                a.u.w = __builtin_amdgcn_perm(f1, f1, 0x03030202u) & 0x3F803F80u;
                acc[r][0] = __builtin_amdgcn_mfma_f32_16x16x32_bf16(a.b, bf0.b, acc[r][0], 0, 0, 0);
                acc[r][1] = __builtin_amdgcn_mfma_f32_16x16x32_bf16(a.b, bf1.b, acc[r][1], 0, 0, 0);
            }
        }
        __syncthreads();
    }

    // ---- phase 3: step B — S (bf16, via LDS transpose) @ Wt2, wave-K-split ----
    uint16_t* SAw = SA + w * (6 * 16 * 40);
#pragma unroll
    for (int r = 0; r < 6; ++r)
#pragma unroll
        for (int ef = 0; ef < 2; ++ef)
#pragma unroll
            for (int reg = 0; reg < 4; ++reg)
                SAw[(r * 16 + q * 4 + reg) * 40 + ef * 16 + m] = f2bf(acc[r][ef][reg]);
    // own-wave LDS readback: no barrier needed
    f32x4 c2[8];
#pragma unroll
    for (int nf = 0; nf < 8; ++nf) c2[nf] = (f32x4){0.f, 0.f, 0.f, 0.f};
    const uint16_t* Wb = Wt2 + w * 32 + q * 8;
#pragma unroll
    for (int r = 0; r < 6; ++r) {
        U4B af; af.u = *(const uint4*)&SAw[(r * 16 + m) * 40 + q * 8];
#pragma unroll
        for (int nf = 0; nf < 8; ++nf) {
            U4B bw; bw.u = *(const uint4*)&Wb[(size_t)(nf * 16 + m) * 768 + r * 128];
            c2[nf] = __builtin_amdgcn_mfma_f32_16x16x32_bf16(af.b, bw.b, c2[nf], 0, 0, 0);
        }
    }
#pragma unroll
    for (int nf = 0; nf < 8; ++nf)
#pragma unroll
        for (int reg = 0; reg < 4; ++reg)
            partial[w * (16 * 132) + (q * 4 + reg) * 132 + nf * 16 + m] = c2[nf][reg];
    __syncthreads();

    // ---- epilogue: reduce 4 partials + sym + cnt_r*bias ----
    {
        const int j = tid >> 4, e0 = (tid & 15) * 8;
        float a8[8];
#pragma unroll
        for (int k = 0; k < 8; ++k) a8[k] = 0.f;
#pragma unroll
        for (int w4 = 0; w4 < 4; ++w4) {
            const float* Pp = &partial[w4 * 2112 + j * 132 + e0];
            float4 u0 = *(const float4*)Pp;
            float4 u1 = *(const float4*)(Pp + 4);
            a8[0] += u0.x; a8[1] += u0.y; a8[2] += u0.z; a8[3] += u0.w;
            a8[4] += u1.x; a8[5] += u1.y; a8[6] += u1.z; a8[7] += u1.w;
        }
        float cf[6];
#pragma unroll
        for (int r = 0; r < 6; ++r) cf[r] = cntF[j * 8 + r];
#pragma unroll
        for (int k = 0; k < 8; ++k) {
            float bs = 0.f;
#pragma unroll
            for (int r = 0; r < 6; ++r) bs += cf[r] * biasS[r * 128 + e0 + k];
            a8[k] += bs;
        }
        size_t o = ((size_t)(b * 1024 + j0 + j) << 7) + e0;
        float4 s0 = *(const float4*)&sym[o];
        float4 s1 = *(const float4*)&sym[o + 4];
        float4 o0 = { s0.x + a8[0], s0.y + a8[1], s0.z + a8[2], s0.w + a8[3] };
        float4 o1 = { s1.x + a8[4], s1.y + a8[5], s1.z + a8[6], s1.w + a8[7] };
        *(float4*)&out[o] = o0;
        *(float4*)&out[o + 4] = o1;
    }
}

extern "C" void kernel_launch(void* const* d_in, const int* in_sizes, int n_in,
                              void* d_out, int out_size, void* d_ws, size_t ws_size,
                              hipStream_t stream) {
    const float* symbols   = (const float*)d_in[0];  // [8,1024,128]
    const float* positions = (const float*)d_in[1];  // [8,1024,2]
    const float* W         = (const float*)d_in[2];  // [6,128,128]
    const float* bias      = (const float*)d_in[3];  // [6,128]
    float* out             = (float*)d_out;          // [8,1024,128]

    char* ws = (char*)d_ws;
    uint16_t* symT = (uint16_t*)ws;                  // 8*128*1024 bf16 = 2,097,152 B
    uint16_t* Wt2  = (uint16_t*)(ws + 2097152);      // 128*768 bf16   =   196,608 B

    prep_kernel<<<352, 256, 0, stream>>>(symbols, W, symT, Wt2);
    fused_kernel<<<512, 256, 0, stream>>>(symbols, positions, symT, Wt2, bias, out);
}

// Round 7
// 129.028 us; speedup vs baseline: 3.1928x; 1.0026x over previous
//
#include <hip/hip_runtime.h>
#include <stdint.h>

// out[b,j,:] = sym[b,j,:] + sum_{i!=j} (sym[b,i,:] @ W[rel(i,j)].T + bias[rel(i,j)])
// B=8, N=1024, D=128, 6 relations.
//
// Linearity rewrite:  agg[j] = sum_r (sum_{i!=j, rel=r} sym[i]) @ W[r].T + cnt_r(j)*bias[r]
//  1. prep: symT bf16 [8][128 e][1024 i] (transpose), Wt2 bf16 [128 e'][768 k]
//  2. fused: classify -> masked MFMA (S_r = M_r @ symT) -> S @ Wt2 -> + sym + cnt*bias
//
// R7 fix: __launch_bounds__(256, 1) on fused — R6's plain (256) made the compiler
// cap at 88 VGPRs and spill acc/pf to scratch (WRITE_SIZE 66.5 MB vs 4.2 ideal,
// ~60 us of HBM round-trip). LDS-bound at 2 blocks/CU, so 512-VGPR budget is free.

typedef __attribute__((ext_vector_type(8))) short bf16x8;
typedef __attribute__((ext_vector_type(4))) float f32x4;
union U4B { uint4 u; bf16x8 b; };

__device__ __forceinline__ uint16_t f2bf(float f) {
    union { float f; uint32_t u; } v; v.f = f;
    uint32_t u = v.u;
    uint32_t r = (u + 0x7FFFu + ((u >> 16) & 1u)) >> 16;  // RNE
    return (uint16_t)r;
}

// ---------------------------------------------------------------------------
// prep: blocks 0..255: transpose X[b][i][e] fp32 -> symT[b][e][i] bf16 (64x64 tiles)
//       blocks 256..351: permute W[r][e'][e] fp32 -> Wt2[e'][r*128+e] bf16
// T pitch 65: read banks 2-way (was 8-way at 68), writes conflict-free.
// ---------------------------------------------------------------------------
__global__ __launch_bounds__(256)
void prep_kernel(const float* __restrict__ X, const float* __restrict__ W,
                 uint16_t* __restrict__ symT, uint16_t* __restrict__ Wt2) {
    const int blk = blockIdx.x, tid = threadIdx.x;
    if (blk < 256) {
        __shared__ float T[64 * 65];
        const int b = blk & 7, z = blk >> 3, it = z & 15, et = z >> 4;
        const int i0 = it * 64, e0 = et * 64;
        const float4* Xf = (const float4*)X;
#pragma unroll
        for (int s = 0; s < 4; ++s) {
            int il = s * 16 + (tid >> 4), e4 = tid & 15;
            float4 v = Xf[((size_t)b << 15) + (size_t)((i0 + il) << 5) + (e0 >> 2) + e4];
            T[il * 65 + e4 * 4 + 0] = v.x;
            T[il * 65 + e4 * 4 + 1] = v.y;
            T[il * 65 + e4 * 4 + 2] = v.z;
            T[il * 65 + e4 * 4 + 3] = v.w;
        }
        __syncthreads();
#pragma unroll
        for (int s = 0; s < 4; ++s) {
            int el = s * 16 + (tid >> 4), il4 = tid & 15;
            uint16_t h0 = f2bf(T[(il4 * 4 + 0) * 65 + el]);
            uint16_t h1 = f2bf(T[(il4 * 4 + 1) * 65 + el]);
            uint16_t h2 = f2bf(T[(il4 * 4 + 2) * 65 + el]);
            uint16_t h3 = f2bf(T[(il4 * 4 + 3) * 65 + el]);
            uint2 pk = { (uint32_t)h0 | ((uint32_t)h1 << 16),
                         (uint32_t)h2 | ((uint32_t)h3 << 16) };
            *(uint2*)&symT[((size_t)b << 17) + ((size_t)(e0 + el) << 10) + i0 + il4 * 4] = pk;
        }
    } else {
        int g = (blk - 256) * 256 + tid;          // 0..24575
        float4 v = ((const float4*)W)[g];
        int r = g >> 12, rem = g & 4095, ep = rem >> 5, e4 = rem & 31;
        uint16_t h0 = f2bf(v.x), h1 = f2bf(v.y), h2 = f2bf(v.z), h3 = f2bf(v.w);
        uint2 pk = { (uint32_t)h0 | ((uint32_t)h1 << 16),
                     (uint32_t)h2 | ((uint32_t)h3 << 16) };
        *(uint2*)&Wt2[(size_t)ep * 768 + r * 128 + e4 * 4] = pk;
    }
}

// ---------------------------------------------------------------------------
// fused kernel: grid 512 = 8b x 64jt (16 j per block), 256 thr = 4 e-waves.
// ---------------------------------------------------------------------------
#define RELDW 258

__global__ __launch_bounds__(256, 1)   // 512-VGPR budget: no spills (R6: 66 MB scratch)
void fused_kernel(const float* __restrict__ sym, const float* __restrict__ pos,
                  const uint16_t* __restrict__ symT, const uint16_t* __restrict__ Wt2,
                  const float* __restrict__ bias, float* __restrict__ out) {
    __shared__ __align__(16) char smem[76288];
    // z1 @0     : posS 8192 | symTS 128*136*2=34816 | SA 4*6*16*40*2=30720
    // z2 @34816 : rel32 16*258*4=16512 | partial 4*16*132*4=33792
    // z3 @68608 : cntP 16*16*8*2=4096 ; z4 @72704: cntF 16*8*4=512 ; z5 @73216: biasS 3072
    float2*   posS   = (float2*)smem;
    uint16_t* symTS  = (uint16_t*)smem;
    uint16_t* SA     = (uint16_t*)smem;
    uint32_t* rel32  = (uint32_t*)(smem + 34816);
    float*    partial= (float*)(smem + 34816);
    uint16_t* cntP   = (uint16_t*)(smem + 68608);
    float*    cntF   = (float*)(smem + 72704);
    float*    biasS  = (float*)(smem + 73216);

    const int blk = blockIdx.x;
    const int b = blk & 7, jt = blk >> 3, j0 = jt * 16;
    const int tid = threadIdx.x;
    const int w = tid >> 6, lane = tid & 63, m = lane & 15, q = lane >> 4;

    const uint16_t* symTb = symT + ((size_t)b << 17);

    // prefetch chunk 0 (registers; latency hidden under classify)
    uint4 pf[8];
#pragma unroll
    for (int s = 0; s < 8; ++s) {
        int f = s * 256 + tid, e = f >> 4, seg = f & 15;
        pf[s] = *(const uint4*)&symTb[(e << 10) + seg * 8];
    }

    // ---- phase 0: stage pos + bias ----
    const float2* pos2 = (const float2*)pos + ((size_t)b << 10);
#pragma unroll
    for (int k = 0; k < 4; ++k) posS[tid + k * 256] = pos2[tid + k * 256];
#pragma unroll
    for (int k = 0; k < 3; ++k) biasS[tid + k * 256] = bias[tid + k * 256];
    __syncthreads();

    // ---- phase 1: classify (one-hot bytes) + packed popcount counts ----
    {
        const int mm = tid & 15, grp = tid >> 4;
        const int j = j0 + mm;
        const float2 pj = posS[j];
        uint32_t a0 = 0, a1 = 0, a2 = 0, a3 = 0, a4 = 0, a5 = 0;
        uint32_t* dst = &rel32[mm * RELDW + grp * 16];
#pragma unroll
        for (int s = 0; s < 16; ++s) {
            uint32_t word = 0;
#pragma unroll
            for (int qq = 0; qq < 4; ++qq) {
                int i = grp * 64 + s * 4 + qq;
                float2 pi = posS[i];
                float dx = pj.x - pi.x, dy = pj.y - pi.y;
                // faithful priority chain of _get_relation_type
                int r = (dy > 0.5f) ? 0
                      : (dy < -0.5f) ? 1
                      : (dx < -0.5f) ? 2
                      : (dx > 0.5f)  ? 3
                      : (fabsf(dx) < 0.3f && fabsf(dy) < 0.3f) ? 4
                      : 5;
                uint32_t oh = (i == j) ? 0u : (1u << r);
                word |= oh << (8 * qq);
            }
            dst[s] = word;
            a0 += word & 0x01010101u;
            a1 += (word >> 1) & 0x01010101u;
            a2 += (word >> 2) & 0x01010101u;
            a3 += (word >> 3) & 0x01010101u;
            a4 += (word >> 4) & 0x01010101u;
            a5 += (word >> 5) & 0x01010101u;
        }
        uint16_t* cp = &cntP[(mm * 16 + grp) * 8];
        cp[0] = (uint16_t)((a0 * 0x01010101u) >> 24);
        cp[1] = (uint16_t)((a1 * 0x01010101u) >> 24);
        cp[2] = (uint16_t)((a2 * 0x01010101u) >> 24);
        cp[3] = (uint16_t)((a3 * 0x01010101u) >> 24);
        cp[4] = (uint16_t)((a4 * 0x01010101u) >> 24);
        cp[5] = (uint16_t)((a5 * 0x01010101u) >> 24);
    }
    __syncthreads();
    if (tid < 96) {   // cnt reduce: cntF[j][r]
        int j2 = tid / 6, r2 = tid - j2 * 6;
        int s = 0;
#pragma unroll
        for (int g = 0; g < 16; ++g) s += cntP[(j2 * 16 + g) * 8 + r2];
        cntF[j2 * 8 + r2] = (float)s;
    }
    // (cntF consumed only after later barriers)

    // ---- phase 2: step A — 8 chunks of 128 i ----
    f32x4 acc[6][2];
#pragma unroll
    for (int r = 0; r < 6; ++r)
#pragma unroll
        for (int ef = 0; ef < 2; ++ef) acc[r][ef] = (f32x4){0.f, 0.f, 0.f, 0.f};

    for (int c = 0; c < 8; ++c) {
#pragma unroll
        for (int s = 0; s < 8; ++s) {
            int f = s * 256 + tid, e = f >> 4, seg = f & 15;
            *(uint4*)&symTS[e * 136 + seg * 8] = pf[s];
        }
        __syncthreads();
        if (c < 7) {
#pragma unroll
            for (int s = 0; s < 8; ++s) {
                int f = s * 256 + tid, e = f >> 4, seg = f & 15;
                pf[s] = *(const uint4*)&symTb[(e << 10) + (c + 1) * 128 + seg * 8];
            }
        }
        const uint16_t* bt0 = &symTS[(w * 32 + m) * 136];
        const uint16_t* bt1 = &symTS[(w * 32 + 16 + m) * 136];
        const uint32_t* cr = &rel32[m * RELDW + c * 32 + q * 2];
#pragma unroll
        for (int ks = 0; ks < 4; ++ks) {
            U4B bf0, bf1;
            bf0.u = *(const uint4*)(bt0 + ks * 32 + q * 8);
            bf1.u = *(const uint4*)(bt1 + ks * 32 + q * 8);
            uint2 cw = *(const uint2*)(cr + ks * 8);
#pragma unroll
            for (int r = 0; r < 6; ++r) {
                const uint32_t rm = 0x01010101u << r;
                uint32_t z0 = (cw.x & rm) + 0x7F7F7F7Fu;
                uint32_t z1 = (cw.y & rm) + 0x7F7F7F7Fu;
                uint32_t y0 = z0 & 0x80808080u, y1 = z1 & 0x80808080u;
                uint32_t f0 = y0 | (y0 - (y0 >> 7));
                uint32_t f1 = y1 | (y1 - (y1 >> 7));
                U4B a;
                a.u.x = __builtin_amdgcn_perm(f0, f0, 0x01010000u) & 0x3F803F80u;
                a.u.y = __builtin_amdgcn_perm(f0, f0, 0x03030202u) & 0x3F803F80u;
                a.u.z = __builtin_amdgcn_perm(f1, f1, 0x01010000u) & 0x3F803F80u;
                a.u.w = __builtin_amdgcn_perm(f1, f1, 0x03030202u) & 0x3F803F80u;
                acc[r][0] = __builtin_amdgcn_mfma_f32_16x16x32_bf16(a.b, bf0.b, acc[r][0], 0, 0, 0);
                acc[r][1] = __builtin_amdgcn_mfma_f32_16x16x32_bf16(a.b, bf1.b, acc[r][1], 0, 0, 0);
            }
        }
        __syncthreads();
    }

    // ---- phase 3: step B — S (bf16, via LDS transpose) @ Wt2, wave-K-split ----
    uint16_t* SAw = SA + w * (6 * 16 * 40);
#pragma unroll
    for (int r = 0; r < 6; ++r)
#pragma unroll
        for (int ef = 0; ef < 2; ++ef)
#pragma unroll
            for (int reg = 0; reg < 4; ++reg)
                SAw[(r * 16 + q * 4 + reg) * 40 + ef * 16 + m] = f2bf(acc[r][ef][reg]);
    // own-wave LDS readback: no barrier needed
    f32x4 c2[8];
#pragma unroll
    for (int nf = 0; nf < 8; ++nf) c2[nf] = (f32x4){0.f, 0.f, 0.f, 0.f};
    const uint16_t* Wb = Wt2 + w * 32 + q * 8;
#pragma unroll
    for (int r = 0; r < 6; ++r) {
        U4B af; af.u = *(const uint4*)&SAw[(r * 16 + m) * 40 + q * 8];
#pragma unroll
        for (int nf = 0; nf < 8; ++nf) {
            U4B bw; bw.u = *(const uint4*)&Wb[(size_t)(nf * 16 + m) * 768 + r * 128];
            c2[nf] = __builtin_amdgcn_mfma_f32_16x16x32_bf16(af.b, bw.b, c2[nf], 0, 0, 0);
        }
    }
#pragma unroll
    for (int nf = 0; nf < 8; ++nf)
#pragma unroll
        for (int reg = 0; reg < 4; ++reg)
            partial[w * (16 * 132) + (q * 4 + reg) * 132 + nf * 16 + m] = c2[nf][reg];
    __syncthreads();

    // ---- epilogue: reduce 4 partials + sym + cnt_r*bias ----
    {
        const int j = tid >> 4, e0 = (tid & 15) * 8;
        float a8[8];
#pragma unroll
        for (int k = 0; k < 8; ++k) a8[k] = 0.f;
#pragma unroll
        for (int w4 = 0; w4 < 4; ++w4) {
            const float* Pp = &partial[w4 * 2112 + j * 132 + e0];
            float4 u0 = *(const float4*)Pp;
            float4 u1 = *(const float4*)(Pp + 4);
            a8[0] += u0.x; a8[1] += u0.y; a8[2] += u0.z; a8[3] += u0.w;
            a8[4] += u1.x; a8[5] += u1.y; a8[6] += u1.z; a8[7] += u1.w;
        }
        float cf[6];
#pragma unroll
        for (int r = 0; r < 6; ++r) cf[r] = cntF[j * 8 + r];
#pragma unroll
        for (int k = 0; k < 8; ++k) {
            float bs = 0.f;
#pragma unroll
            for (int r = 0; r < 6; ++r) bs += cf[r] * biasS[r * 128 + e0 + k];
            a8[k] += bs;
        }
        size_t o = ((size_t)(b * 1024 + j0 + j) << 7) + e0;
        float4 s0 = *(const float4*)&sym[o];
        float4 s1 = *(const float4*)&sym[o + 4];
        float4 o0 = { s0.x + a8[0], s0.y + a8[1], s0.z + a8[2], s0.w + a8[3] };
        float4 o1 = { s1.x + a8[4], s1.y + a8[5], s1.z + a8[6], s1.w + a8[7] };
        *(float4*)&out[o] = o0;
        *(float4*)&out[o + 4] = o1;
    }
}

extern "C" void kernel_launch(void* const* d_in, const int* in_sizes, int n_in,
                              void* d_out, int out_size, void* d_ws, size_t ws_size,
                              hipStream_t stream) {
    const float* symbols   = (const float*)d_in[0];  // [8,1024,128]
    const float* positions = (const float*)d_in[1];  // [8,1024,2]
    const float* W         = (const float*)d_in[2];  // [6,128,128]
    const float* bias      = (const float*)d_in[3];  // [6,128]
    float* out             = (float*)d_out;          // [8,1024,128]

    char* ws = (char*)d_ws;
    uint16_t* symT = (uint16_t*)ws;                  // 8*128*1024 bf16 = 2,097,152 B
    uint16_t* Wt2  = (uint16_t*)(ws + 2097152);      // 128*768 bf16   =   196,608 B

    prep_kernel<<<352, 256, 0, stream>>>(symbols, W, symT, Wt2);
    fused_kernel<<<512, 256, 0, stream>>>(symbols, positions, symT, Wt2, bias, out);
}

// Round 8
// 113.332 us; speedup vs baseline: 3.6350x; 1.1385x over previous
//
#include <hip/hip_runtime.h>
#include <stdint.h>

// out[b,j,:] = sym[b,j,:] + sum_{i!=j} (sym[b,i,:] @ W[rel(i,j)].T + bias[rel(i,j)])
// B=8, N=1024, D=128, 6 relations.
//
// Linearity rewrite:  agg[j] = sum_r (sum_{i!=j, rel=r} sym[i]) @ W[r].T + cnt_r(j)*bias[r]
//  1. prep: symT bf16 [8][128 e][1024 i]; WtB bf16 blocked [kb(24)][e'(128)][kc(32)]
//     where k = kb*32+kc = r*128+e, WtB[..] = W[r][e'][e]  (MFMA-frag-coalesced).
//  2. fused (512 thr = 8 e-waves): classify -> masked MFMA (S_r = M_r @ symT)
//     -> S @ Wt (K=768, 4-way K-split) -> + sym + cnt*bias.
//
// R8: 512-thr blocks halve per-thread regs (R6/R7 spilled ~474 B/thread: WRITE_SIZE
// 66 MB vs 4 ideal); mul_u24 mask synth; blocked Wt for 16-line frag loads.

typedef __attribute__((ext_vector_type(8))) short bf16x8;
typedef __attribute__((ext_vector_type(4))) float f32x4;
union U4B { uint4 u; bf16x8 b; };

#if defined(__has_builtin)
#  if __has_builtin(__builtin_amdgcn_mul_u24)
#    define OH_MUL24 1
#  endif
#endif

__device__ __forceinline__ uint16_t f2bf(float f) {
    union { float f; uint32_t u; } v; v.f = f;
    uint32_t u = v.u;
    uint32_t r = (u + 0x7FFFu + ((u >> 16) & 1u)) >> 16;  // RNE
    return (uint16_t)r;
}

// ---------------------------------------------------------------------------
// prep: blocks 0..255: transpose X[b][i][e] fp32 -> symT[b][e][i] bf16 (64x64 tiles)
//       blocks 256..351: W[r][ep][e] fp32 -> WtB[(kb*128+ep)*32+kc] bf16, k=r*128+e
// ---------------------------------------------------------------------------
__global__ __launch_bounds__(256)
void prep_kernel(const float* __restrict__ X, const float* __restrict__ W,
                 uint16_t* __restrict__ symT, uint16_t* __restrict__ WtB) {
    const int blk = blockIdx.x, tid = threadIdx.x;
    if (blk < 256) {
        __shared__ float T[64 * 65];
        const int b = blk & 7, z = blk >> 3, it = z & 15, et = z >> 4;
        const int i0 = it * 64, e0 = et * 64;
        const float4* Xf = (const float4*)X;
#pragma unroll
        for (int s = 0; s < 4; ++s) {
            int il = s * 16 + (tid >> 4), e4 = tid & 15;
            float4 v = Xf[((size_t)b << 15) + (size_t)((i0 + il) << 5) + (e0 >> 2) + e4];
            T[il * 65 + e4 * 4 + 0] = v.x;
            T[il * 65 + e4 * 4 + 1] = v.y;
            T[il * 65 + e4 * 4 + 2] = v.z;
            T[il * 65 + e4 * 4 + 3] = v.w;
        }
        __syncthreads();
#pragma unroll
        for (int s = 0; s < 4; ++s) {
            int el = s * 16 + (tid >> 4), il4 = tid & 15;
            uint16_t h0 = f2bf(T[(il4 * 4 + 0) * 65 + el]);
            uint16_t h1 = f2bf(T[(il4 * 4 + 1) * 65 + el]);
            uint16_t h2 = f2bf(T[(il4 * 4 + 2) * 65 + el]);
            uint16_t h3 = f2bf(T[(il4 * 4 + 3) * 65 + el]);
            uint2 pk = { (uint32_t)h0 | ((uint32_t)h1 << 16),
                         (uint32_t)h2 | ((uint32_t)h3 << 16) };
            *(uint2*)&symT[((size_t)b << 17) + ((size_t)(e0 + el) << 10) + i0 + il4 * 4] = pk;
        }
    } else {
        int g = (blk - 256) * 256 + tid;          // 0..24575 float4s of W
        float4 v = ((const float4*)W)[g];
        int r = g >> 12, rem = g & 4095, ep = rem >> 5, e4 = rem & 31;
        int kb = r * 4 + (e4 >> 3);               // k = r*128 + e4*4+t
        int kc = (e4 & 7) * 4;
        uint16_t h0 = f2bf(v.x), h1 = f2bf(v.y), h2 = f2bf(v.z), h3 = f2bf(v.w);
        uint2 pk = { (uint32_t)h0 | ((uint32_t)h1 << 16),
                     (uint32_t)h2 | ((uint32_t)h3 << 16) };
        *(uint2*)&WtB[((size_t)(kb * 128 + ep)) * 32 + kc] = pk;
    }
}

// ---------------------------------------------------------------------------
// fused kernel: grid 512 = 8b x 64jt (16 j per block), 512 thr = 8 waves.
// Phase 2: wave w owns e-block [w*16, w*16+16); acc[6] per thread.
// Phase 3: K-split g=w>>1 (192 k each), e-half h=w&1; partials reduced in LDS.
// ---------------------------------------------------------------------------
#define RELDW 258
#define SP 776    // SA pitch (hw): 16-B aligned rows, 2-way-max frag reads

__global__ __launch_bounds__(512, 2)
void fused_kernel(const float* __restrict__ sym, const float* __restrict__ pos,
                  const uint16_t* __restrict__ symT, const uint16_t* __restrict__ WtB,
                  const float* __restrict__ bias, float* __restrict__ out) {
    // zoneA @0 (34816): posS(8192) -> symTS(128*136*2) -> SA(16*776*2=24832)
    // zoneB @34816 (33792): rel32(16512) + cntP @+16512 (6144) -> partial(33792)
    // cntF @68608 (512); biasS @69120 (3072). total 72192 B -> 2 blocks/CU.
    __shared__ __align__(16) char smem[72192];
    float2*   posS    = (float2*)smem;
    uint16_t* symTS   = (uint16_t*)smem;
    uint16_t* SA      = (uint16_t*)smem;
    uint32_t* rel32   = (uint32_t*)(smem + 34816);
    float*    partial = (float*)(smem + 34816);
    uint16_t* cntP    = (uint16_t*)(smem + 34816 + 16512);
    float*    cntF    = (float*)(smem + 68608);
    float*    biasS   = (float*)(smem + 69120);

    const int blk = blockIdx.x;
    const int b = blk & 7, jt = blk >> 3, j0 = jt * 16;
    const int tid = threadIdx.x;
    const int w = tid >> 6, lane = tid & 63, m = lane & 15, q = lane >> 4;

    const uint16_t* symTb = symT + ((size_t)b << 17);

    // prefetch chunk 0 (registers; latency hidden under classify)
    uint4 pf[4];
#pragma unroll
    for (int s = 0; s < 4; ++s) {
        int f = s * 512 + tid, e = f >> 4, seg = f & 15;
        pf[s] = *(const uint4*)&symTb[(e << 10) + seg * 8];
    }

    // ---- phase 0: stage pos + bias ----
    const float2* pos2 = (const float2*)pos + ((size_t)b << 10);
    posS[tid] = pos2[tid];
    posS[tid + 512] = pos2[tid + 512];
    biasS[tid] = bias[tid];
    if (tid < 256) biasS[tid + 512] = bias[tid + 512];
    __syncthreads();

    // ---- phase 1: classify (one-hot bytes) + packed popcount counts ----
    {
        const int mm = tid & 15, grp = tid >> 4;      // grp 0..31: 32 i's each
        const int j = j0 + mm;
        const float2 pj = posS[j];
        uint32_t a0 = 0, a1 = 0, a2 = 0, a3 = 0, a4 = 0, a5 = 0;
        uint32_t* dst = &rel32[mm * RELDW + grp * 8];
#pragma unroll
        for (int s = 0; s < 8; ++s) {
            uint32_t word = 0;
#pragma unroll
            for (int qq = 0; qq < 4; ++qq) {
                int i = grp * 32 + s * 4 + qq;
                float2 pi = posS[i];
                float dx = pj.x - pi.x, dy = pj.y - pi.y;
                // faithful priority chain of _get_relation_type
                int r = (dy > 0.5f) ? 0
                      : (dy < -0.5f) ? 1
                      : (dx < -0.5f) ? 2
                      : (dx > 0.5f)  ? 3
                      : (fabsf(dx) < 0.3f && fabsf(dy) < 0.3f) ? 4
                      : 5;
                uint32_t oh = (i == j) ? 0u : (1u << r);
                word |= oh << (8 * qq);
            }
            dst[s] = word;
            a0 += word & 0x01010101u;
            a1 += (word >> 1) & 0x01010101u;
            a2 += (word >> 2) & 0x01010101u;
            a3 += (word >> 3) & 0x01010101u;
            a4 += (word >> 4) & 0x01010101u;
            a5 += (word >> 5) & 0x01010101u;
        }
        uint16_t* cp = &cntP[(mm * 32 + grp) * 6];
        cp[0] = (uint16_t)((a0 * 0x01010101u) >> 24);
        cp[1] = (uint16_t)((a1 * 0x01010101u) >> 24);
        cp[2] = (uint16_t)((a2 * 0x01010101u) >> 24);
        cp[3] = (uint16_t)((a3 * 0x01010101u) >> 24);
        cp[4] = (uint16_t)((a4 * 0x01010101u) >> 24);
        cp[5] = (uint16_t)((a5 * 0x01010101u) >> 24);
    }
    __syncthreads();
    if (tid < 96) {   // cntF[j][r] (cntP dead after this; zoneB reused by partial)
        int j2 = tid / 6, r2 = tid - j2 * 6;
        int s = 0;
#pragma unroll
        for (int g = 0; g < 32; ++g) s += cntP[(j2 * 32 + g) * 6 + r2];
        cntF[j2 * 8 + r2] = (float)s;
    }

    // ---- phase 2: masked GEMM, 8 chunks of 128 i ----
    f32x4 acc[6];
#pragma unroll
    for (int r = 0; r < 6; ++r) acc[r] = (f32x4){0.f, 0.f, 0.f, 0.f};

    for (int c = 0; c < 8; ++c) {
#pragma unroll
        for (int s = 0; s < 4; ++s) {
            int f = s * 512 + tid, e = f >> 4, seg = f & 15;
            *(uint4*)&symTS[e * 136 + seg * 8] = pf[s];
        }
        __syncthreads();
        if (c < 7) {
#pragma unroll
            for (int s = 0; s < 4; ++s) {
                int f = s * 512 + tid, e = f >> 4, seg = f & 15;
                pf[s] = *(const uint4*)&symTb[(e << 10) + (c + 1) * 128 + seg * 8];
            }
        }
        const uint16_t* bt = &symTS[(w * 16 + m) * 136];
        const uint32_t* cr = &rel32[m * RELDW + c * 32 + q * 2];
#pragma unroll
        for (int ks = 0; ks < 4; ++ks) {
            U4B bfr;
            bfr.u = *(const uint4*)(bt + ks * 32 + q * 8);
            uint2 cw = *(const uint2*)(cr + ks * 8);
            // byte -> halfword expansion (shared across r)
            uint32_t hx01 = __builtin_amdgcn_perm(cw.x, cw.x, 0x01010000u) & 0x00FF00FFu;
            uint32_t hx23 = __builtin_amdgcn_perm(cw.x, cw.x, 0x03030202u) & 0x00FF00FFu;
            uint32_t hy01 = __builtin_amdgcn_perm(cw.y, cw.y, 0x01010000u) & 0x00FF00FFu;
            uint32_t hy23 = __builtin_amdgcn_perm(cw.y, cw.y, 0x03030202u) & 0x00FF00FFu;
#pragma unroll
            for (int r = 0; r < 6; ++r) {
                const uint32_t rm = 0x00010001u << r;
                U4B a;
#ifdef OH_MUL24
                const uint32_t mc = 0x3F80u >> r;   // 2^r * mc == 0x3F80 (bf16 1.0)
                a.u.x = (uint32_t)__builtin_amdgcn_mul_u24((int)(hx01 & rm), (int)mc);
                a.u.y = (uint32_t)__builtin_amdgcn_mul_u24((int)(hx23 & rm), (int)mc);
                a.u.z = (uint32_t)__builtin_amdgcn_mul_u24((int)(hy01 & rm), (int)mc);
                a.u.w = (uint32_t)__builtin_amdgcn_mul_u24((int)(hy23 & rm), (int)mc);
#else
                uint32_t g;
                g = hx01 & rm; a.u.x = (g << (14 - r)) - (g << (7 - r));
                g = hx23 & rm; a.u.y = (g << (14 - r)) - (g << (7 - r));
                g = hy01 & rm; a.u.z = (g << (14 - r)) - (g << (7 - r));
                g = hy23 & rm; a.u.w = (g << (14 - r)) - (g << (7 - r));
#endif
                acc[r] = __builtin_amdgcn_mfma_f32_16x16x32_bf16(a.b, bfr.b, acc[r], 0, 0, 0);
            }
        }
        __syncthreads();
    }

    // ---- phase 3: S (bf16, via LDS) @ WtB, 4-way K-split over wave pairs ----
#pragma unroll
    for (int r = 0; r < 6; ++r)
#pragma unroll
        for (int reg = 0; reg < 4; ++reg)
            SA[(q * 4 + reg) * SP + r * 128 + w * 16 + m] = f2bf(acc[r][reg]);
    __syncthreads();

    {
        const int g = w >> 1, h = w & 1;
        f32x4 c2[4];
#pragma unroll
        for (int nf = 0; nf < 4; ++nf) c2[nf] = (f32x4){0.f, 0.f, 0.f, 0.f};
#pragma unroll
        for (int kf = 0; kf < 6; ++kf) {
            U4B af;
            af.u = *(const uint4*)&SA[m * SP + g * 192 + kf * 32 + q * 8];
            const int kb = g * 6 + kf;
#pragma unroll
            for (int nf = 0; nf < 4; ++nf) {
                U4B bw;
                bw.u = *(const uint4*)&WtB[((size_t)(kb * 128 + h * 64 + nf * 16 + m)) * 32 + q * 8];
                c2[nf] = __builtin_amdgcn_mfma_f32_16x16x32_bf16(af.b, bw.b, c2[nf], 0, 0, 0);
            }
        }
#pragma unroll
        for (int nf = 0; nf < 4; ++nf)
#pragma unroll
            for (int reg = 0; reg < 4; ++reg)
                partial[g * 2112 + (q * 4 + reg) * 132 + h * 64 + nf * 16 + m] = c2[nf][reg];
    }
    __syncthreads();

    // ---- epilogue: reduce 4 K-split partials + sym + cnt_r*bias ----
    {
        const int j = tid >> 5, e0 = (tid & 31) * 4;
        float4 a4 = {0.f, 0.f, 0.f, 0.f};
#pragma unroll
        for (int g4 = 0; g4 < 4; ++g4) {
            float4 u = *(const float4*)&partial[g4 * 2112 + j * 132 + e0];
            a4.x += u.x; a4.y += u.y; a4.z += u.z; a4.w += u.w;
        }
#pragma unroll
        for (int r = 0; r < 6; ++r) {
            float cf = cntF[j * 8 + r];
            float4 bb = *(const float4*)&biasS[r * 128 + e0];
            a4.x += cf * bb.x; a4.y += cf * bb.y; a4.z += cf * bb.z; a4.w += cf * bb.w;
        }
        size_t o = ((size_t)(b * 1024 + j0 + j) << 7) + e0;
        float4 s0 = *(const float4*)&sym[o];
        float4 o0 = { s0.x + a4.x, s0.y + a4.y, s0.z + a4.z, s0.w + a4.w };
        *(float4*)&out[o] = o0;
    }
}

extern "C" void kernel_launch(void* const* d_in, const int* in_sizes, int n_in,
                              void* d_out, int out_size, void* d_ws, size_t ws_size,
                              hipStream_t stream) {
    const float* symbols   = (const float*)d_in[0];  // [8,1024,128]
    const float* positions = (const float*)d_in[1];  // [8,1024,2]
    const float* W         = (const float*)d_in[2];  // [6,128,128]
    const float* bias      = (const float*)d_in[3];  // [6,128]
    float* out             = (float*)d_out;          // [8,1024,128]

    char* ws = (char*)d_ws;
    uint16_t* symT = (uint16_t*)ws;                  // 8*128*1024 bf16 = 2,097,152 B
    uint16_t* WtB  = (uint16_t*)(ws + 2097152);      // 24*128*32 bf16 =   196,608 B

    prep_kernel<<<352, 256, 0, stream>>>(symbols, W, symT, WtB);
    fused_kernel<<<512, 512, 0, stream>>>(symbols, positions, symT, WtB, bias, out);
}

// Round 9
// 112.676 us; speedup vs baseline: 3.6561x; 1.0058x over previous
//
#include <hip/hip_runtime.h>
#include <stdint.h>

// out[b,j,:] = sym[b,j,:] + sum_{i!=j} (sym[b,i,:] @ W[rel(i,j)].T + bias[rel(i,j)])
// B=8, N=1024, D=128, 6 relations.
//
// Linearity rewrite:  agg[j] = sum_r (sum_{i!=j, rel=r} sym[i]) @ W[r].T + cnt_r(j)*bias[r]
//  1. prep: symT bf16 [8][128 e][1024 i]; WtB bf16 blocked [kb(24)][e'(128)][kc(32)]
//  2. fused (512 thr = 8 e-waves): classify -> masked MFMA (S_r = M_r @ symT)
//     -> S @ Wt (K=768, 4-way K-split) -> + sym + cnt*bias.
//
// R9: amdgpu_waves_per_eu(2,4) — R8 still spilled (VGPR=52, WRITE_SIZE 77 MB vs
// 4.2 ideal): launch_bounds' 2nd arg is only a MIN-occupancy bound; the allocator
// heuristic targeted 8 waves/EU and spilled. LDS (72 KB -> 2 blocks/CU) caps real
// occupancy at 4 waves/EU, so capping the target at 4 frees a 128-VGPR budget.

typedef __attribute__((ext_vector_type(8))) short bf16x8;
typedef __attribute__((ext_vector_type(4))) float f32x4;
union U4B { uint4 u; bf16x8 b; };

#if defined(__has_builtin)
#  if __has_builtin(__builtin_amdgcn_mul_u24)
#    define OH_MUL24 1
#  endif
#endif

__device__ __forceinline__ uint16_t f2bf(float f) {
    union { float f; uint32_t u; } v; v.f = f;
    uint32_t u = v.u;
    uint32_t r = (u + 0x7FFFu + ((u >> 16) & 1u)) >> 16;  // RNE
    return (uint16_t)r;
}

// ---------------------------------------------------------------------------
// prep: blocks 0..255: transpose X[b][i][e] fp32 -> symT[b][e][i] bf16 (64x64 tiles)
//       blocks 256..351: W[r][ep][e] fp32 -> WtB[(kb*128+ep)*32+kc] bf16, k=r*128+e
// ---------------------------------------------------------------------------
__global__ __launch_bounds__(256)
void prep_kernel(const float* __restrict__ X, const float* __restrict__ W,
                 uint16_t* __restrict__ symT, uint16_t* __restrict__ WtB) {
    const int blk = blockIdx.x, tid = threadIdx.x;
    if (blk < 256) {
        __shared__ float T[64 * 65];
        const int b = blk & 7, z = blk >> 3, it = z & 15, et = z >> 4;
        const int i0 = it * 64, e0 = et * 64;
        const float4* Xf = (const float4*)X;
#pragma unroll
        for (int s = 0; s < 4; ++s) {
            int il = s * 16 + (tid >> 4), e4 = tid & 15;
            float4 v = Xf[((size_t)b << 15) + (size_t)((i0 + il) << 5) + (e0 >> 2) + e4];
            T[il * 65 + e4 * 4 + 0] = v.x;
            T[il * 65 + e4 * 4 + 1] = v.y;
            T[il * 65 + e4 * 4 + 2] = v.z;
            T[il * 65 + e4 * 4 + 3] = v.w;
        }
        __syncthreads();
#pragma unroll
        for (int s = 0; s < 4; ++s) {
            int el = s * 16 + (tid >> 4), il4 = tid & 15;
            uint16_t h0 = f2bf(T[(il4 * 4 + 0) * 65 + el]);
            uint16_t h1 = f2bf(T[(il4 * 4 + 1) * 65 + el]);
            uint16_t h2 = f2bf(T[(il4 * 4 + 2) * 65 + el]);
            uint16_t h3 = f2bf(T[(il4 * 4 + 3) * 65 + el]);
            uint2 pk = { (uint32_t)h0 | ((uint32_t)h1 << 16),
                         (uint32_t)h2 | ((uint32_t)h3 << 16) };
            *(uint2*)&symT[((size_t)b << 17) + ((size_t)(e0 + el) << 10) + i0 + il4 * 4] = pk;
        }
    } else {
        int g = (blk - 256) * 256 + tid;          // 0..24575 float4s of W
        float4 v = ((const float4*)W)[g];
        int r = g >> 12, rem = g & 4095, ep = rem >> 5, e4 = rem & 31;
        int kb = r * 4 + (e4 >> 3);               // k = r*128 + e4*4+t
        int kc = (e4 & 7) * 4;
        uint16_t h0 = f2bf(v.x), h1 = f2bf(v.y), h2 = f2bf(v.z), h3 = f2bf(v.w);
        uint2 pk = { (uint32_t)h0 | ((uint32_t)h1 << 16),
                     (uint32_t)h2 | ((uint32_t)h3 << 16) };
        *(uint2*)&WtB[((size_t)(kb * 128 + ep)) * 32 + kc] = pk;
    }
}

// ---------------------------------------------------------------------------
// fused kernel: grid 512 = 8b x 64jt (16 j per block), 512 thr = 8 waves.
// Phase 2: wave w owns e-block [w*16, w*16+16); acc[6] per thread.
// Phase 3: K-split g=w>>1 (192 k each), e-half h=w&1; partials reduced in LDS.
// ---------------------------------------------------------------------------
#define RELDW 258
#define SP 776    // SA pitch (hw): 16-B aligned rows, 2-way-max frag reads

__global__ __launch_bounds__(512)
__attribute__((amdgpu_waves_per_eu(2, 4)))   // cap occupancy target: 128+ VGPR budget, no spills
void fused_kernel(const float* __restrict__ sym, const float* __restrict__ pos,
                  const uint16_t* __restrict__ symT, const uint16_t* __restrict__ WtB,
                  const float* __restrict__ bias, float* __restrict__ out) {
    // zoneA @0 (34816): posS(8192) -> symTS(128*136*2) -> SA(16*776*2=24832)
    // zoneB @34816 (33792): rel32(16512) + cntP @+16512 (6144) -> partial(33792)
    // cntF @68608 (512); biasS @69120 (3072). total 72192 B -> 2 blocks/CU.
    __shared__ __align__(16) char smem[72192];
    float2*   posS    = (float2*)smem;
    uint16_t* symTS   = (uint16_t*)smem;
    uint16_t* SA      = (uint16_t*)smem;
    uint32_t* rel32   = (uint32_t*)(smem + 34816);
    float*    partial = (float*)(smem + 34816);
    uint16_t* cntP    = (uint16_t*)(smem + 34816 + 16512);
    float*    cntF    = (float*)(smem + 68608);
    float*    biasS   = (float*)(smem + 69120);

    const int blk = blockIdx.x;
    const int b = blk & 7, jt = blk >> 3, j0 = jt * 16;
    const int tid = threadIdx.x;
    const int w = tid >> 6, lane = tid & 63, m = lane & 15, q = lane >> 4;

    const uint16_t* symTb = symT + ((size_t)b << 17);

    // prefetch chunk 0 (registers; latency hidden under classify)
    uint4 pf[4];
#pragma unroll
    for (int s = 0; s < 4; ++s) {
        int f = s * 512 + tid, e = f >> 4, seg = f & 15;
        pf[s] = *(const uint4*)&symTb[(e << 10) + seg * 8];
    }

    // ---- phase 0: stage pos + bias ----
    const float2* pos2 = (const float2*)pos + ((size_t)b << 10);
    posS[tid] = pos2[tid];
    posS[tid + 512] = pos2[tid + 512];
    biasS[tid] = bias[tid];
    if (tid < 256) biasS[tid + 512] = bias[tid + 512];
    __syncthreads();

    // ---- phase 1: classify (one-hot bytes) + packed popcount counts ----
    {
        const int mm = tid & 15, grp = tid >> 4;      // grp 0..31: 32 i's each
        const int j = j0 + mm;
        const float2 pj = posS[j];
        uint32_t a0 = 0, a1 = 0, a2 = 0, a3 = 0, a4 = 0, a5 = 0;
        uint32_t* dst = &rel32[mm * RELDW + grp * 8];
#pragma unroll
        for (int s = 0; s < 8; ++s) {
            uint32_t word = 0;
#pragma unroll
            for (int qq = 0; qq < 4; ++qq) {
                int i = grp * 32 + s * 4 + qq;
                float2 pi = posS[i];
                float dx = pj.x - pi.x, dy = pj.y - pi.y;
                // faithful priority chain of _get_relation_type
                int r = (dy > 0.5f) ? 0
                      : (dy < -0.5f) ? 1
                      : (dx < -0.5f) ? 2
                      : (dx > 0.5f)  ? 3
                      : (fabsf(dx) < 0.3f && fabsf(dy) < 0.3f) ? 4
                      : 5;
                uint32_t oh = (i == j) ? 0u : (1u << r);
                word |= oh << (8 * qq);
            }
            dst[s] = word;
            a0 += word & 0x01010101u;
            a1 += (word >> 1) & 0x01010101u;
            a2 += (word >> 2) & 0x01010101u;
            a3 += (word >> 3) & 0x01010101u;
            a4 += (word >> 4) & 0x01010101u;
            a5 += (word >> 5) & 0x01010101u;
        }
        uint16_t* cp = &cntP[(mm * 32 + grp) * 6];
        cp[0] = (uint16_t)((a0 * 0x01010101u) >> 24);
        cp[1] = (uint16_t)((a1 * 0x01010101u) >> 24);
        cp[2] = (uint16_t)((a2 * 0x01010101u) >> 24);
        cp[3] = (uint16_t)((a3 * 0x01010101u) >> 24);
        cp[4] = (uint16_t)((a4 * 0x01010101u) >> 24);
        cp[5] = (uint16_t)((a5 * 0x01010101u) >> 24);
    }
    __syncthreads();
    if (tid < 96) {   // cntF[j][r] (cntP dead after this; zoneB reused by partial)
        int j2 = tid / 6, r2 = tid - j2 * 6;
        int s = 0;
#pragma unroll
        for (int g = 0; g < 32; ++g) s += cntP[(j2 * 32 + g) * 6 + r2];
        cntF[j2 * 8 + r2] = (float)s;
    }

    // ---- phase 2: masked GEMM, 8 chunks of 128 i ----
    f32x4 acc[6];
#pragma unroll
    for (int r = 0; r < 6; ++r) acc[r] = (f32x4){0.f, 0.f, 0.f, 0.f};

    for (int c = 0; c < 8; ++c) {
#pragma unroll
        for (int s = 0; s < 4; ++s) {
            int f = s * 512 + tid, e = f >> 4, seg = f & 15;
            *(uint4*)&symTS[e * 136 + seg * 8] = pf[s];
        }
        __syncthreads();
        if (c < 7) {
#pragma unroll
            for (int s = 0; s < 4; ++s) {
                int f = s * 512 + tid, e = f >> 4, seg = f & 15;
                pf[s] = *(const uint4*)&symTb[(e << 10) + (c + 1) * 128 + seg * 8];
            }
        }
        const uint16_t* bt = &symTS[(w * 16 + m) * 136];
        const uint32_t* cr = &rel32[m * RELDW + c * 32 + q * 2];
#pragma unroll
        for (int ks = 0; ks < 4; ++ks) {
            U4B bfr;
            bfr.u = *(const uint4*)(bt + ks * 32 + q * 8);
            uint2 cw = *(const uint2*)(cr + ks * 8);
            // byte -> halfword expansion (shared across r)
            uint32_t hx01 = __builtin_amdgcn_perm(cw.x, cw.x, 0x01010000u) & 0x00FF00FFu;
            uint32_t hx23 = __builtin_amdgcn_perm(cw.x, cw.x, 0x03030202u) & 0x00FF00FFu;
            uint32_t hy01 = __builtin_amdgcn_perm(cw.y, cw.y, 0x01010000u) & 0x00FF00FFu;
            uint32_t hy23 = __builtin_amdgcn_perm(cw.y, cw.y, 0x03030202u) & 0x00FF00FFu;
#pragma unroll
            for (int r = 0; r < 6; ++r) {
                const uint32_t rm = 0x00010001u << r;
                U4B a;
#ifdef OH_MUL24
                const uint32_t mc = 0x3F80u >> r;   // 2^r * mc == 0x3F80 (bf16 1.0)
                a.u.x = (uint32_t)__builtin_amdgcn_mul_u24((int)(hx01 & rm), (int)mc);
                a.u.y = (uint32_t)__builtin_amdgcn_mul_u24((int)(hx23 & rm), (int)mc);
                a.u.z = (uint32_t)__builtin_amdgcn_mul_u24((int)(hy01 & rm), (int)mc);
                a.u.w = (uint32_t)__builtin_amdgcn_mul_u24((int)(hy23 & rm), (int)mc);
#else
                uint32_t g;
                g = hx01 & rm; a.u.x = (g << (14 - r)) - (g << (7 - r));
                g = hx23 & rm; a.u.y = (g << (14 - r)) - (g << (7 - r));
                g = hy01 & rm; a.u.z = (g << (14 - r)) - (g << (7 - r));
                g = hy23 & rm; a.u.w = (g << (14 - r)) - (g << (7 - r));
#endif
                acc[r] = __builtin_amdgcn_mfma_f32_16x16x32_bf16(a.b, bfr.b, acc[r], 0, 0, 0);
            }
        }
        __syncthreads();
    }

    // ---- phase 3: S (bf16, via LDS) @ WtB, 4-way K-split over wave pairs ----
#pragma unroll
    for (int r = 0; r < 6; ++r)
#pragma unroll
        for (int reg = 0; reg < 4; ++reg)
            SA[(q * 4 + reg) * SP + r * 128 + w * 16 + m] = f2bf(acc[r][reg]);
    __syncthreads();

    {
        const int g = w >> 1, h = w & 1;
        f32x4 c2[4];
#pragma unroll
        for (int nf = 0; nf < 4; ++nf) c2[nf] = (f32x4){0.f, 0.f, 0.f, 0.f};
#pragma unroll
        for (int kf = 0; kf < 6; ++kf) {
            U4B af;
            af.u = *(const uint4*)&SA[m * SP + g * 192 + kf * 32 + q * 8];
            const int kb = g * 6 + kf;
#pragma unroll
            for (int nf = 0; nf < 4; ++nf) {
                U4B bw;
                bw.u = *(const uint4*)&WtB[((size_t)(kb * 128 + h * 64 + nf * 16 + m)) * 32 + q * 8];
                c2[nf] = __builtin_amdgcn_mfma_f32_16x16x32_bf16(af.b, bw.b, c2[nf], 0, 0, 0);
            }
        }
#pragma unroll
        for (int nf = 0; nf < 4; ++nf)
#pragma unroll
            for (int reg = 0; reg < 4; ++reg)
                partial[g * 2112 + (q * 4 + reg) * 132 + h * 64 + nf * 16 + m] = c2[nf][reg];
    }
    __syncthreads();

    // ---- epilogue: reduce 4 K-split partials + sym + cnt_r*bias ----
    {
        const int j = tid >> 5, e0 = (tid & 31) * 4;
        float4 a4 = {0.f, 0.f, 0.f, 0.f};
#pragma unroll
        for (int g4 = 0; g4 < 4; ++g4) {
            float4 u = *(const float4*)&partial[g4 * 2112 + j * 132 + e0];
            a4.x += u.x; a4.y += u.y; a4.z += u.z; a4.w += u.w;
        }
#pragma unroll
        for (int r = 0; r < 6; ++r) {
            float cf = cntF[j * 8 + r];
            float4 bb = *(const float4*)&biasS[r * 128 + e0];
            a4.x += cf * bb.x; a4.y += cf * bb.y; a4.z += cf * bb.z; a4.w += cf * bb.w;
        }
        size_t o = ((size_t)(b * 1024 + j0 + j) << 7) + e0;
        float4 s0 = *(const float4*)&sym[o];
        float4 o0 = { s0.x + a4.x, s0.y + a4.y, s0.z + a4.z, s0.w + a4.w };
        *(float4*)&out[o] = o0;
    }
}

extern "C" void kernel_launch(void* const* d_in, const int* in_sizes, int n_in,
                              void* d_out, int out_size, void* d_ws, size_t ws_size,
                              hipStream_t stream) {
    const float* symbols   = (const float*)d_in[0];  // [8,1024,128]
    const float* positions = (const float*)d_in[1];  // [8,1024,2]
    const float* W         = (const float*)d_in[2];  // [6,128,128]
    const float* bias      = (const float*)d_in[3];  // [6,128]
    float* out             = (float*)d_out;          // [8,1024,128]

    char* ws = (char*)d_ws;
    uint16_t* symT = (uint16_t*)ws;                  // 8*128*1024 bf16 = 2,097,152 B
    uint16_t* WtB  = (uint16_t*)(ws + 2097152);      // 24*128*32 bf16 =   196,608 B

    prep_kernel<<<352, 256, 0, stream>>>(symbols, W, symT, WtB);
    fused_kernel<<<512, 512, 0, stream>>>(symbols, positions, symT, WtB, bias, out);
}

// Round 10
// 92.214 us; speedup vs baseline: 4.4674x; 1.2219x over previous
//
#include <hip/hip_runtime.h>
#include <stdint.h>

// out[b,j,:] = sym[b,j,:] + sum_{i!=j} (sym[b,i,:] @ W[rel(i,j)].T + bias[rel(i,j)])
// B=8, N=1024, D=128, 6 relations.
//
// Linearity rewrite:  agg[j] = sum_r (sum_{i!=j, rel=r} sym[i]) @ W[r].T + cnt_r(j)*bias[r]
//  1. prep: symT bf16 [8][128 e][1024 i]; WtB bf16 blocked [kb(24)][e'(128)][kc(32)]
//  2. fused (512 thr = 8 e-waves): classify -> masked MFMA (S_r = M_r @ symT)
//     -> S @ Wt (K=768, 4-way K-split) -> + sym + cnt*bias.
//
// R10: R8/R9 spilled ~280 B/thread (VGPR=52 < ~62 live; WRITE_SIZE 77 MB vs 4.2
// ideal). Fix is structural: global_load_lds DMA staging (no pf[] registers, no
// staging VALU, async under compute), XOR-swizzled LDS layouts instead of padding
// (DMA needs lane-contiguous dests), counts recomputed in epilogue from rel32
// (kills cntP/cntF/biasS). LDS = exactly 80 KB -> 2 blocks/CU.

typedef __attribute__((ext_vector_type(8))) short bf16x8;
typedef __attribute__((ext_vector_type(4))) float f32x4;
union U4B { uint4 u; bf16x8 b; };

#if defined(__has_builtin)
#  if __has_builtin(__builtin_amdgcn_global_load_lds)
#    define HAVE_GLL 1
#  endif
#  if __has_builtin(__builtin_amdgcn_mul_u24)
#    define OH_MUL24 1
#  endif
#endif

__device__ __forceinline__ uint16_t f2bf(float f) {
    union { float f; uint32_t u; } v; v.f = f;
    uint32_t u = v.u;
    uint32_t r = (u + 0x7FFFu + ((u >> 16) & 1u)) >> 16;  // RNE
    return (uint16_t)r;
}

// ---------------------------------------------------------------------------
// prep: blocks 0..255: transpose X[b][i][e] fp32 -> symT[b][e][i] bf16 (64x64 tiles)
//       blocks 256..351: W[r][ep][e] fp32 -> WtB[(kb*128+ep)*32+kc] bf16, k=r*128+e
// ---------------------------------------------------------------------------
__global__ __launch_bounds__(256)
void prep_kernel(const float* __restrict__ X, const float* __restrict__ W,
                 uint16_t* __restrict__ symT, uint16_t* __restrict__ WtB) {
    const int blk = blockIdx.x, tid = threadIdx.x;
    if (blk < 256) {
        __shared__ float T[64 * 65];
        const int b = blk & 7, z = blk >> 3, it = z & 15, et = z >> 4;
        const int i0 = it * 64, e0 = et * 64;
        const float4* Xf = (const float4*)X;
#pragma unroll
        for (int s = 0; s < 4; ++s) {
            int il = s * 16 + (tid >> 4), e4 = tid & 15;
            float4 v = Xf[((size_t)b << 15) + (size_t)((i0 + il) << 5) + (e0 >> 2) + e4];
            T[il * 65 + e4 * 4 + 0] = v.x;
            T[il * 65 + e4 * 4 + 1] = v.y;
            T[il * 65 + e4 * 4 + 2] = v.z;
            T[il * 65 + e4 * 4 + 3] = v.w;
        }
        __syncthreads();
#pragma unroll
        for (int s = 0; s < 4; ++s) {
            int el = s * 16 + (tid >> 4), il4 = tid & 15;
            uint16_t h0 = f2bf(T[(il4 * 4 + 0) * 65 + el]);
            uint16_t h1 = f2bf(T[(il4 * 4 + 1) * 65 + el]);
            uint16_t h2 = f2bf(T[(il4 * 4 + 2) * 65 + el]);
            uint16_t h3 = f2bf(T[(il4 * 4 + 3) * 65 + el]);
            uint2 pk = { (uint32_t)h0 | ((uint32_t)h1 << 16),
                         (uint32_t)h2 | ((uint32_t)h3 << 16) };
            *(uint2*)&symT[((size_t)b << 17) + ((size_t)(e0 + el) << 10) + i0 + il4 * 4] = pk;
        }
    } else {
        int g = (blk - 256) * 256 + tid;          // 0..24575 float4s of W
        float4 v = ((const float4*)W)[g];
        int r = g >> 12, rem = g & 4095, ep = rem >> 5, e4 = rem & 31;
        int kb = r * 4 + (e4 >> 3);               // k = r*128 + e4*4+t
        int kc = (e4 & 7) * 4;
        uint16_t h0 = f2bf(v.x), h1 = f2bf(v.y), h2 = f2bf(v.z), h3 = f2bf(v.w);
        uint2 pk = { (uint32_t)h0 | ((uint32_t)h1 << 16),
                     (uint32_t)h2 | ((uint32_t)h3 << 16) };
        *(uint2*)&WtB[((size_t)(kb * 128 + ep)) * 32 + kc] = pk;
    }
}

// ---------------------------------------------------------------------------
// fused kernel: grid 512 = 8b x 64jt (16 j per block), 512 thr = 8 waves.
// LDS map (81920 B -> 2 blocks/CU):
//   @0     symTS[2] double buffer, 32768 B each, 16B segs XOR-swizzled
//          (seg' = seg ^ (e&15)); buf1 doubles as posS (8 KB) during classify;
//          after phase 2 the region holds SA (24832 B @0) + partial (33792 @24832)
//   @65536 rel32: 16 j x 256 dwords, dword-pair swizzle (u ^ 2m), 16384 B
// ---------------------------------------------------------------------------
#define SP 776

__global__ __launch_bounds__(512)
void fused_kernel(const float* __restrict__ sym, const float* __restrict__ pos,
                  const uint16_t* __restrict__ symT, const uint16_t* __restrict__ WtB,
                  const float* __restrict__ bias, float* __restrict__ out) {
    __shared__ __align__(16) char smem[81920];
    uint16_t* symTS   = (uint16_t*)smem;
    float2*   posS    = (float2*)(smem + 32768);
    uint16_t* SA      = (uint16_t*)smem;
    float*    partial = (float*)(smem + 24832);
    uint32_t* rel32   = (uint32_t*)(smem + 65536);

    const int blk = blockIdx.x;
    const int b = blk & 7, jt = blk >> 3, j0 = jt * 16;
    const int tid = threadIdx.x;
    const int w = tid >> 6, lane = tid & 63, m = lane & 15, q = lane >> 4;

    const uint16_t* symTb = symT + ((size_t)b << 17);

    // staging geometry: issue s covers flat 16B-chunks c16 = s*512 + tid;
    // e = c16>>4, gseg = (c16&15) ^ (e&15); LDS dest byte = c16*16 (lane-contig).
    int goff[4];
#pragma unroll
    for (int s = 0; s < 4; ++s) {
        int c16 = s * 512 + tid;
        int e = c16 >> 4, sg = (c16 & 15) ^ (e & 15);
        goff[s] = (e << 10) + sg * 8;       // hw units; + cidx*128 per chunk
    }
    const int lwb = w * 1024;               // wave-uniform byte base within slab

    auto issue_chunk = [&](int cidx, int bufsel) {
#ifdef HAVE_GLL
#pragma unroll
        for (int s = 0; s < 4; ++s) {
            const uint16_t* gp = symTb + goff[s] + cidx * 128;
            char* lp = smem + bufsel * 32768 + s * 8192 + lwb;   // wave-uniform
            typedef const __attribute__((address_space(1))) uint32_t gu32;
            typedef __attribute__((address_space(3))) uint32_t lu32;
            __builtin_amdgcn_global_load_lds((gu32*)gp, (lu32*)lp, 16, 0, 0);
        }
#else
#pragma unroll
        for (int s = 0; s < 4; ++s) {
            uint4 v = *(const uint4*)(symTb + goff[s] + cidx * 128);
            *(uint4*)(smem + bufsel * 32768 + (s * 512 + tid) * 16) = v;
        }
#endif
    };

    issue_chunk(0, 0);                      // async into buf0, hidden under classify

    // ---- phase 0: stage positions (into buf1 region; dead before buf1's first DMA)
    const float2* pos2 = (const float2*)pos + ((size_t)b << 10);
    posS[tid] = pos2[tid];
    posS[tid + 512] = pos2[tid + 512];
    __syncthreads();

    // ---- phase 1: classify 16 j x 1024 i -> one-hot bytes (0 on diagonal) ----
    {
        const int mm = tid & 15, grp = tid >> 4;    // grp 0..31: 32 i's each
        const int j = j0 + mm;
        const float2 pj = posS[j];
        uint32_t* dst = &rel32[mm * 256];
        const int sw = mm * 2;                      // pair-granular XOR swizzle
#pragma unroll
        for (int s = 0; s < 8; ++s) {
            uint32_t word = 0;
#pragma unroll
            for (int qq = 0; qq < 4; ++qq) {
                int i = grp * 32 + s * 4 + qq;
                float2 pi = posS[i];
                float dx = pj.x - pi.x, dy = pj.y - pi.y;
                // faithful priority chain of _get_relation_type
                int r = (dy > 0.5f) ? 0
                      : (dy < -0.5f) ? 1
                      : (dx < -0.5f) ? 2
                      : (dx > 0.5f)  ? 3
                      : (fabsf(dx) < 0.3f && fabsf(dy) < 0.3f) ? 4
                      : 5;
                uint32_t oh = (i == j) ? 0u : (1u << r);
                word |= oh << (8 * qq);
            }
            dst[(grp * 8 + s) ^ sw] = word;
        }
    }
    __syncthreads();

    // ---- phase 2: masked GEMM, 8 chunks of 128 i, DMA double-buffered ----
    f32x4 acc[6];
#pragma unroll
    for (int r = 0; r < 6; ++r) acc[r] = (f32x4){0.f, 0.f, 0.f, 0.f};

    const int E = w * 16 + m;        // e-row owned by this lane
    const int esw = E & 15;          // == m
    const int csw = m * 2;

    for (int c = 0; c < 8; ++c) {
        if (c < 7) issue_chunk(c + 1, (c + 1) & 1);   // async into other buffer
        const uint16_t* bt = symTS + ((c & 1) << 14) + E * 128;
        const uint32_t* crow = &rel32[m * 256 + c * 32];
#pragma unroll
        for (int ks = 0; ks < 4; ++ks) {
            U4B bfr;
            bfr.u = *(const uint4*)(bt + ((((ks << 2) + q) ^ esw) << 3));
            uint2 cw = *(const uint2*)&crow[(((ks << 3) + (q << 1)) ^ csw)];
            // byte -> halfword expansion (shared across r)
            uint32_t hx01 = __builtin_amdgcn_perm(cw.x, cw.x, 0x01010000u) & 0x00FF00FFu;
            uint32_t hx23 = __builtin_amdgcn_perm(cw.x, cw.x, 0x03030202u) & 0x00FF00FFu;
            uint32_t hy01 = __builtin_amdgcn_perm(cw.y, cw.y, 0x01010000u) & 0x00FF00FFu;
            uint32_t hy23 = __builtin_amdgcn_perm(cw.y, cw.y, 0x03030202u) & 0x00FF00FFu;
#pragma unroll
            for (int r = 0; r < 6; ++r) {
                const uint32_t rm = 0x00010001u << r;
                U4B a;
#ifdef OH_MUL24
                const uint32_t mc = 0x3F80u >> r;   // 2^r * mc == 0x3F80 (bf16 1.0)
                a.u.x = (uint32_t)__builtin_amdgcn_mul_u24((int)(hx01 & rm), (int)mc);
                a.u.y = (uint32_t)__builtin_amdgcn_mul_u24((int)(hx23 & rm), (int)mc);
                a.u.z = (uint32_t)__builtin_amdgcn_mul_u24((int)(hy01 & rm), (int)mc);
                a.u.w = (uint32_t)__builtin_amdgcn_mul_u24((int)(hy23 & rm), (int)mc);
#else
                uint32_t g2;
                g2 = hx01 & rm; a.u.x = (g2 << (14 - r)) - (g2 << (7 - r));
                g2 = hx23 & rm; a.u.y = (g2 << (14 - r)) - (g2 << (7 - r));
                g2 = hy01 & rm; a.u.z = (g2 << (14 - r)) - (g2 << (7 - r));
                g2 = hy23 & rm; a.u.w = (g2 << (14 - r)) - (g2 << (7 - r));
#endif
                acc[r] = __builtin_amdgcn_mfma_f32_16x16x32_bf16(a.b, bfr.b, acc[r], 0, 0, 0);
            }
        }
        __syncthreads();   // drains next-chunk DMA + releases read buffer
    }

    // ---- phase 3: S (bf16, via LDS) @ WtB, 4-way K-split over wave pairs ----
#pragma unroll
    for (int r = 0; r < 6; ++r)
#pragma unroll
        for (int reg = 0; reg < 4; ++reg)
            SA[(q * 4 + reg) * SP + r * 128 + w * 16 + m] = f2bf(acc[r][reg]);
    __syncthreads();

    {
        const int g = w >> 1, h = w & 1;
        f32x4 c2[4];
#pragma unroll
        for (int nf = 0; nf < 4; ++nf) c2[nf] = (f32x4){0.f, 0.f, 0.f, 0.f};
#pragma unroll
        for (int kf = 0; kf < 6; ++kf) {
            U4B af;
            af.u = *(const uint4*)&SA[m * SP + g * 192 + kf * 32 + q * 8];
            const int kb = g * 6 + kf;
#pragma unroll
            for (int nf = 0; nf < 4; ++nf) {
                U4B bw;
                bw.u = *(const uint4*)&WtB[((size_t)(kb * 128 + h * 64 + nf * 16 + m)) * 32 + q * 8];
                c2[nf] = __builtin_amdgcn_mfma_f32_16x16x32_bf16(af.b, bw.b, c2[nf], 0, 0, 0);
            }
        }
#pragma unroll
        for (int nf = 0; nf < 4; ++nf)
#pragma unroll
            for (int reg = 0; reg < 4; ++reg)
                partial[g * 2112 + (q * 4 + reg) * 132 + h * 64 + nf * 16 + m] = c2[nf][reg];
    }
    __syncthreads();

    // ---- epilogue: reduce K-split partials + sym + cnt_r*bias ----
    // counts recomputed from rel32 (intact; swizzle is a row-internal permutation)
    {
        const int j = tid >> 5, t = tid & 31, e0 = t << 2;
        const uint32_t* row = &rel32[j * 256 + t * 8];
        uint32_t s0 = 0, s1 = 0, s2 = 0, s3 = 0, s4 = 0, s5 = 0;
#pragma unroll
        for (int k = 0; k < 8; ++k) {
            uint32_t wd = row[k];
            s0 += wd & 0x01010101u;        s1 += (wd >> 1) & 0x01010101u;
            s2 += (wd >> 2) & 0x01010101u; s3 += (wd >> 3) & 0x01010101u;
            s4 += (wd >> 4) & 0x01010101u; s5 += (wd >> 5) & 0x01010101u;
        }
        int cnt[6];
        cnt[0] = (int)((s0 * 0x01010101u) >> 24);
        cnt[1] = (int)((s1 * 0x01010101u) >> 24);
        cnt[2] = (int)((s2 * 0x01010101u) >> 24);
        cnt[3] = (int)((s3 * 0x01010101u) >> 24);
        cnt[4] = (int)((s4 * 0x01010101u) >> 24);
        cnt[5] = (int)((s5 * 0x01010101u) >> 24);
#pragma unroll
        for (int off = 1; off < 32; off <<= 1)
#pragma unroll
            for (int r = 0; r < 6; ++r)
                cnt[r] += __shfl_xor(cnt[r], off, 64);   // half-wave reduce

        float4 a4 = {0.f, 0.f, 0.f, 0.f};
#pragma unroll
        for (int g4 = 0; g4 < 4; ++g4) {
            float4 u = *(const float4*)&partial[g4 * 2112 + j * 132 + e0];
            a4.x += u.x; a4.y += u.y; a4.z += u.z; a4.w += u.w;
        }
#pragma unroll
        for (int r = 0; r < 6; ++r) {
            float cf = (float)cnt[r];
            float4 bb = *(const float4*)&bias[r * 128 + e0];
            a4.x += cf * bb.x; a4.y += cf * bb.y; a4.z += cf * bb.z; a4.w += cf * bb.w;
        }
        size_t o = ((size_t)(b * 1024 + j0 + j) << 7) + e0;
        float4 sv = *(const float4*)&sym[o];
        float4 ov = { sv.x + a4.x, sv.y + a4.y, sv.z + a4.z, sv.w + a4.w };
        *(float4*)&out[o] = ov;
    }
}

extern "C" void kernel_launch(void* const* d_in, const int* in_sizes, int n_in,
                              void* d_out, int out_size, void* d_ws, size_t ws_size,
                              hipStream_t stream) {
    const float* symbols   = (const float*)d_in[0];  // [8,1024,128]
    const float* positions = (const float*)d_in[1];  // [8,1024,2]
    const float* W         = (const float*)d_in[2];  // [6,128,128]
    const float* bias      = (const float*)d_in[3];  // [6,128]
    float* out             = (float*)d_out;          // [8,1024,128]

    char* ws = (char*)d_ws;
    uint16_t* symT = (uint16_t*)ws;                  // 8*128*1024 bf16 = 2,097,152 B
    uint16_t* WtB  = (uint16_t*)(ws + 2097152);      // 24*128*32 bf16 =   196,608 B

    prep_kernel<<<352, 256, 0, stream>>>(symbols, W, symT, WtB);
    fused_kernel<<<512, 512, 0, stream>>>(symbols, positions, symT, WtB, bias, out);
}